// Round 2
// baseline (269.177 us; speedup 1.0000x reference)
//
#include <hip/hip_runtime.h>

// ---------------------------------------------------------------------------
// MultiHeadAttention: B=2, S=2048, D=1024, H=16, hd=64
// Interleaved head split: Q[b,h,s,d] = proj[b,s, d*16+h]; scale = 1/32.
// Precision: split-bf16 (hi+lo) emulated-fp32 for Q/K path. V/attn/out bf16.
// v11: defer-max (T13) in flash_attn. The 16x shfl_xor row-max reduce +
// alpha rescale only runs when a lane-local check (__all(lmax-m<=8)) fails
// (~10-15% of iters); skip path writes P=exp2(sc-m_old) directly (P<=256,
// bf16 rel-precision scale-invariant; (o,l) stay consistently 2^-m scaled so
// combine math unchanged). Cuts 16/56 LDS-pipe ops + the serial swizzle
// chain per iter. + s_setprio(1) around MFMA clusters (T5). Split-KV kept.
// ---------------------------------------------------------------------------

typedef __bf16 bf16x8 __attribute__((ext_vector_type(8)));
typedef float  f32x4  __attribute__((ext_vector_type(4)));

#define S_LEN  2048
#define DMODEL 1024
#define NHEADS 16
#define HDIM   64
#define LOG2E  1.44269504088896340736f

__device__ __forceinline__ void gll16(const __bf16* g, __bf16* l) {
    __builtin_amdgcn_global_load_lds(
        (const __attribute__((address_space(1))) unsigned int*)g,
        (__attribute__((address_space(3))) unsigned int*)l, 16, 0, 0);
}

// ---------------------------------------------------------------------------
// Fused prep: id<4096 -> f32->(hi,lo) conv of x; else weight transposes.
// z=0: qw split col-permuted; z=1: kw; z=2: vw plain; z=3: ow k-permuted.
// perm(i) = (i&15)*64 + (i>>4).
// ---------------------------------------------------------------------------
__global__ __launch_bounds__(256) void prep_all(
    const float* __restrict__ x,
    const float* __restrict__ qw, const float* __restrict__ kw,
    const float* __restrict__ vw, const float* __restrict__ ow,
    __bf16* __restrict__ xhi, __bf16* __restrict__ xlo,
    __bf16* __restrict__ qwthi, __bf16* __restrict__ qwtlo,
    __bf16* __restrict__ kwthi, __bf16* __restrict__ kwtlo,
    __bf16* __restrict__ vwt,  __bf16* __restrict__ owt) {
    __shared__ float tile[32][33];
    int id = blockIdx.x;
    if (id < 4096) {
        int i = id * 256 + threadIdx.x;
        float4 v = ((const float4*)x)[i];
        __bf16 h0 = (__bf16)v.x, h1 = (__bf16)v.y, h2 = (__bf16)v.z, h3 = (__bf16)v.w;
        ushort4 hh, ll;
        hh.x = __builtin_bit_cast(unsigned short, h0);
        hh.y = __builtin_bit_cast(unsigned short, h1);
        hh.z = __builtin_bit_cast(unsigned short, h2);
        hh.w = __builtin_bit_cast(unsigned short, h3);
        ll.x = __builtin_bit_cast(unsigned short, (__bf16)(v.x - (float)h0));
        ll.y = __builtin_bit_cast(unsigned short, (__bf16)(v.y - (float)h1));
        ll.z = __builtin_bit_cast(unsigned short, (__bf16)(v.z - (float)h2));
        ll.w = __builtin_bit_cast(unsigned short, (__bf16)(v.w - (float)h3));
        ((ushort4*)xhi)[i] = hh;
        ((ushort4*)xlo)[i] = ll;
        return;
    }
    int rid = id - 4096;
    int z = rid >> 10;                       // 0..3
    int bx = rid & 31, by = (rid >> 5) & 31;
    const float* w = (z == 0) ? qw : (z == 1) ? kw : (z == 2) ? vw : ow;
    int n0 = bx * 32, k0 = by * 32;
    int tx = threadIdx.x & 31, ty = threadIdx.x >> 5;
#pragma unroll
    for (int i = 0; i < 32; i += 8)
        tile[ty + i][tx] = w[(k0 + ty + i) * DMODEL + n0 + tx];
    __syncthreads();
#pragma unroll
    for (int i = 0; i < 32; i += 8) {
        float f = tile[tx][ty + i];           // = w[k0+tx][n0+ty+i]
        int k = k0 + tx, n = n0 + ty + i;
        if (z <= 1) {
            __bf16 fh = (__bf16)f;
            __bf16 fl = (__bf16)(f - (float)fh);
            int c = (n & 15) * 64 + (n >> 4);
            if (z == 0) { qwthi[c * DMODEL + k] = fh; qwtlo[c * DMODEL + k] = fl; }
            else        { kwthi[c * DMODEL + k] = fh; kwtlo[c * DMODEL + k] = fl; }
        } else if (z == 2) {
            vwt[n * DMODEL + k] = (__bf16)f;
        } else {
            int ck = (k & 15) * 64 + (k >> 4);
            owt[n * DMODEL + ck] = (__bf16)f;
        }
    }
}

// ---------------------------------------------------------------------------
// QKV projections. grid (8, 32, 3), LDS chunk-swizzled (2-way frag reads).
// z=0: Q = x @ qw (split-bf16, scale log2e/32), merged [m][c] hi/lo out.
// z=1: K likewise, scale 1.
// z=2: V^T = vwt @ x^T (plain), out [bh][d][s].
// ---------------------------------------------------------------------------
__global__ __launch_bounds__(256) void qkv_gemm(
    const __bf16* __restrict__ xhi, const __bf16* __restrict__ xlo,
    const __bf16* __restrict__ qwthi, const __bf16* __restrict__ qwtlo,
    const __bf16* __restrict__ kwthi, const __bf16* __restrict__ kwtlo,
    const __bf16* __restrict__ vwt,
    __bf16* __restrict__ Qhi, __bf16* __restrict__ Qlo,
    __bf16* __restrict__ Khi, __bf16* __restrict__ Klo,
    __bf16* __restrict__ Vt) {
    __shared__ __bf16 Ash[128][32], Asl[128][32], Bsh[128][32], Bsl[128][32];
    int mode = blockIdx.z;
    int tid  = threadIdx.x;
    int wave = tid >> 6, lane = tid & 63;
    int quad = lane >> 4, l15 = lane & 15;
    int wm = (wave >> 1) * 64, wn = (wave & 1) * 64;
    int grow = lane >> 2;
    int gcol = (((lane & 3) - ((lane >> 3) & 3)) & 3) * 8;   // swizzled source chunk
    int sA   = ((quad + (l15 >> 1)) & 3) * 8;                // swizzled frag slot
    const int K = DMODEL;

    if (mode < 2) {
        const __bf16* Bh = mode ? kwthi : qwthi;
        const __bf16* Bl = mode ? kwtlo : qwtlo;
        int m0 = blockIdx.y * 128, n0 = blockIdx.x * 128;
        f32x4 acc[4][4] = {};
        for (int k0 = 0; k0 < K; k0 += 32) {
            __syncthreads();
#pragma unroll
            for (int ps = 0; ps < 2; ps++) {
                int row = ps * 64 + wave * 16;
                gll16(&xhi[(m0 + row + grow) * K + k0 + gcol], &Ash[row][0]);
                gll16(&xlo[(m0 + row + grow) * K + k0 + gcol], &Asl[row][0]);
                gll16(&Bh [(n0 + row + grow) * K + k0 + gcol], &Bsh[row][0]);
                gll16(&Bl [(n0 + row + grow) * K + k0 + gcol], &Bsl[row][0]);
            }
            __syncthreads();
            bf16x8 ah[4], al[4], bh[4], bl[4];
#pragma unroll
            for (int mi = 0; mi < 4; mi++) {
                ah[mi] = *(const bf16x8*)&Ash[wm + mi * 16 + l15][sA];
                al[mi] = *(const bf16x8*)&Asl[wm + mi * 16 + l15][sA];
            }
#pragma unroll
            for (int ni = 0; ni < 4; ni++) {
                bh[ni] = *(const bf16x8*)&Bsh[wn + ni * 16 + l15][sA];
                bl[ni] = *(const bf16x8*)&Bsl[wn + ni * 16 + l15][sA];
            }
#pragma unroll
            for (int mi = 0; mi < 4; mi++)
#pragma unroll
                for (int ni = 0; ni < 4; ni++) {
                    acc[mi][ni] = __builtin_amdgcn_mfma_f32_16x16x32_bf16(ah[mi], bh[ni], acc[mi][ni], 0, 0, 0);
                    acc[mi][ni] = __builtin_amdgcn_mfma_f32_16x16x32_bf16(ah[mi], bl[ni], acc[mi][ni], 0, 0, 0);
                    acc[mi][ni] = __builtin_amdgcn_mfma_f32_16x16x32_bf16(al[mi], bh[ni], acc[mi][ni], 0, 0, 0);
                }
        }
        float oscale = mode ? 1.0f : 0.03125f * LOG2E;
        __bf16* Ohi = mode ? Khi : Qhi;
        __bf16* Olo = mode ? Klo : Qlo;
#pragma unroll
        for (int mi = 0; mi < 4; mi++)
#pragma unroll
            for (int ni = 0; ni < 4; ni++)
#pragma unroll
                for (int rg = 0; rg < 4; rg++) {
                    int m = m0 + wm + mi * 16 + quad * 4 + rg;
                    int n = n0 + wn + ni * 16 + l15;     // n == merged channel
                    float v = acc[mi][ni][rg] * oscale;
                    size_t idx = (size_t)m * DMODEL + n;
                    __bf16 vh = (__bf16)v;
                    Ohi[idx] = vh;
                    Olo[idx] = (__bf16)(v - (float)vh);
                }
    } else {
        // V^T: A = vwt (channel rows), B = xhi (x rows); C[ch][xm]
        int ch0 = blockIdx.x * 128, xm0 = blockIdx.y * 128;
        f32x4 acc[4][4] = {};
        for (int k0 = 0; k0 < K; k0 += 32) {
            __syncthreads();
#pragma unroll
            for (int ps = 0; ps < 2; ps++) {
                int row = ps * 64 + wave * 16;
                gll16(&vwt[(ch0 + row + grow) * K + k0 + gcol], &Ash[row][0]);
                gll16(&xhi[(xm0 + row + grow) * K + k0 + gcol], &Bsh[row][0]);
            }
            __syncthreads();
            bf16x8 af[4], bfr[4];
#pragma unroll
            for (int mi = 0; mi < 4; mi++)
                af[mi] = *(const bf16x8*)&Ash[wm + mi * 16 + l15][sA];
#pragma unroll
            for (int ni = 0; ni < 4; ni++)
                bfr[ni] = *(const bf16x8*)&Bsh[wn + ni * 16 + l15][sA];
#pragma unroll
            for (int mi = 0; mi < 4; mi++)
#pragma unroll
                for (int ni = 0; ni < 4; ni++)
                    acc[mi][ni] = __builtin_amdgcn_mfma_f32_16x16x32_bf16(
                        af[mi], bfr[ni], acc[mi][ni], 0, 0, 0);
        }
#pragma unroll
        for (int mi = 0; mi < 4; mi++)
#pragma unroll
            for (int ni = 0; ni < 4; ni++)
#pragma unroll
                for (int rg = 0; rg < 4; rg++) {
                    int ch = ch0 + wm + mi * 16 + quad * 4 + rg;
                    int xm = xm0 + wn + ni * 16 + l15;
                    int b = xm >> 11, s = xm & 2047;
                    int h = ch & 15,  d = ch >> 4;
                    Vt[((size_t)(b * NHEADS + h) * HDIM + d) * S_LEN + s] =
                        (__bf16)acc[mi][ni][rg];
                }
    }
}

// ---------------------------------------------------------------------------
// Output projection: out[m][n] = attnb[m][:] . owt[n][:], fp32 out.
// 64x128 tiles -> grid (8,64) = 512 blocks. Swizzled LDS.
// ---------------------------------------------------------------------------
__global__ __launch_bounds__(256) void out_gemm(const __bf16* __restrict__ A,
                                                const __bf16* __restrict__ Bt,
                                                float* __restrict__ out) {
    __shared__ __bf16 As[64][32];
    __shared__ __bf16 Bs[128][32];
    int tid  = threadIdx.x;
    int wave = tid >> 6, lane = tid & 63;
    int quad = lane >> 4, l15 = lane & 15;
    int m0 = blockIdx.y * 64, n0 = blockIdx.x * 128;
    int wm = (wave >> 1) * 32, wn = (wave & 1) * 64;
    int grow = lane >> 2;
    int gcol = (((lane & 3) - ((lane >> 3) & 3)) & 3) * 8;
    int sA   = ((quad + (l15 >> 1)) & 3) * 8;
    const int K = DMODEL;
    f32x4 acc[2][4] = {};

    for (int k0 = 0; k0 < K; k0 += 32) {
        __syncthreads();
        gll16(&A[(m0 + wave * 16 + grow) * K + k0 + gcol], &As[wave * 16][0]);
#pragma unroll
        for (int ps = 0; ps < 2; ps++) {
            int row = ps * 64 + wave * 16;
            gll16(&Bt[(n0 + row + grow) * K + k0 + gcol], &Bs[row][0]);
        }
        __syncthreads();
        bf16x8 af[2], bfr[4];
#pragma unroll
        for (int mi = 0; mi < 2; mi++)
            af[mi] = *(const bf16x8*)&As[wm + mi * 16 + l15][sA];
#pragma unroll
        for (int ni = 0; ni < 4; ni++)
            bfr[ni] = *(const bf16x8*)&Bs[wn + ni * 16 + l15][sA];
#pragma unroll
        for (int mi = 0; mi < 2; mi++)
#pragma unroll
            for (int ni = 0; ni < 4; ni++)
                acc[mi][ni] = __builtin_amdgcn_mfma_f32_16x16x32_bf16(
                    af[mi], bfr[ni], acc[mi][ni], 0, 0, 0);
    }

#pragma unroll
    for (int mi = 0; mi < 2; mi++)
#pragma unroll
        for (int ni = 0; ni < 4; ni++)
#pragma unroll
            for (int rg = 0; rg < 4; rg++) {
                int m = m0 + wm + mi * 16 + quad * 4 + rg;
                int n = n0 + wn + ni * 16 + l15;
                out[(size_t)m * DMODEL + n] = acc[mi][ni][rg];
            }
}

// ---------------------------------------------------------------------------
// Flash attention (v11): split-KV + defer-max.
// id<1024: long tiles t=31..16, each as TWO blocks (KV halves) emitting
//   unnormalized f32 partials (o, m, l) to workspace.
// id>=1024: short tiles t=15..0, single block, final write.
// Defer-max: full shfl-reduce + rescale only when __all(lmax-m<=8) fails.
// ---------------------------------------------------------------------------
__global__ __launch_bounds__(256, 4) void flash_attn(const __bf16* __restrict__ Qhi,
                                                     const __bf16* __restrict__ Qlo,
                                                     const __bf16* __restrict__ Khi,
                                                     const __bf16* __restrict__ Klo,
                                                     const __bf16* __restrict__ Vt,
                                                     __bf16* __restrict__ attn,
                                                     float* __restrict__ po0,
                                                     float* __restrict__ po1,
                                                     float* __restrict__ pml) {
    int id = blockIdx.x;
    int bh, t, i0, i1, part;
    bool split;
    if (id < 1024) {                        // long tiles, 2 KV-half blocks each
        int xcd = id & 7, r = id >> 3;      // r 0..127
        bh = xcd + 8 * (r & 3);             // 4 heads pinned per XCD
        int rr = r >> 2;                    // 0..31
        t = 31 - (rr >> 1);                 // 31..16, longest first
        part = rr & 1;
        int hlf = (t + 1) >> 1;
        i0 = part ? hlf : 0;
        i1 = part ? (t + 1) : hlf;
        split = true;
    } else {                                // short tiles, direct write
        int id2 = id - 1024;
        int xcd = id2 & 7, r = id2 >> 3;    // r 0..63
        bh = xcd + 8 * (r & 3);
        t = 15 - (r >> 2);                  // 15..0
        part = 0; i0 = 0; i1 = t + 1;
        split = false;
    }
    int b = bh >> 4, h = bh & 15;
    const __bf16* Qh_hi = Qhi + (size_t)b * S_LEN * DMODEL + h * HDIM;
    const __bf16* Qh_lo = Qlo + (size_t)b * S_LEN * DMODEL + h * HDIM;
    const __bf16* Kh_hi = Khi + (size_t)b * S_LEN * DMODEL + h * HDIM;
    const __bf16* Kh_lo = Klo + (size_t)b * S_LEN * DMODEL + h * HDIM;
    const __bf16* Vh    = Vt  + (size_t)bh * HDIM * S_LEN;

    int tid = threadIdx.x, wave = tid >> 6, lane = tid & 63;
    int quad = lane >> 4, l15 = lane & 15;

    __shared__ __bf16 KhF[8 * 64 * 8];
    __shared__ __bf16 KlF[8 * 64 * 8];
    __shared__ __bf16 VF [8 * 64 * 8];
    __shared__ __bf16 Ps[4][16][72];

    int c1  = tid >> 6, key = tid & 63;
    int inner = (c1 * 16 + (key & 15)) * 8;
    int rK    = (key >> 4);
    int kdst0 = rK * 512 + inner, kdst1 = (4 + rK) * 512 + inner;
    const __bf16* vrow = Vh + (size_t)key * S_LEN;   // dim = key var

    int q0w = t * 64 + wave * 16;
    bf16x8 aqh0 = *(const bf16x8*)&Qh_hi[(size_t)(q0w + l15) * DMODEL + quad * 8];
    bf16x8 aqh1 = *(const bf16x8*)&Qh_hi[(size_t)(q0w + l15) * DMODEL + 32 + quad * 8];
    bf16x8 aql0 = *(const bf16x8*)&Qh_lo[(size_t)(q0w + l15) * DMODEL + quad * 8];
    bf16x8 aql1 = *(const bf16x8*)&Qh_lo[(size_t)(q0w + l15) * DMODEL + 32 + quad * 8];

    bf16x8 ones;
#pragma unroll
    for (int j = 0; j < 8; j++) ones[j] = (__bf16)1.0f;

    uint4 pk0, pk1, pl0, pl1, pv0, pv1;
    {   // prefetch tile i0
        const __bf16* sk = Kh_hi + (size_t)(i0 * 64 + key) * DMODEL;
        const __bf16* sl = Kh_lo + (size_t)(i0 * 64 + key) * DMODEL;
        pk0 = *(const uint4*)(sk + c1 * 8); pk1 = *(const uint4*)(sk + c1 * 8 + 32);
        pl0 = *(const uint4*)(sl + c1 * 8); pl1 = *(const uint4*)(sl + c1 * 8 + 32);
        pv0 = *(const uint4*)(vrow + i0 * 64 + c1 * 8);
        pv1 = *(const uint4*)(vrow + i0 * 64 + c1 * 8 + 32);
    }

    float m[4] = {-3e38f, -3e38f, -3e38f, -3e38f};
    f32x4 o[4] = {};
    f32x4 ol = {};
    int qrb = q0w + quad * 4;

    for (int i = i0; i < i1; i++) {
        int key0 = i * 64;
        bool diag = (i == t);               // only reachable in last-tile block

        __syncthreads();
        *(uint4*)&KhF[kdst0] = pk0;  *(uint4*)&KhF[kdst1] = pk1;
        *(uint4*)&KlF[kdst0] = pl0;  *(uint4*)&KlF[kdst1] = pl1;
        *(uint4*)&VF [kdst0] = pv0;  *(uint4*)&VF [kdst1] = pv1;
        __syncthreads();

        if (i + 1 < i1) {
            int key0n = (i + 1) * 64;
            const __bf16* sk = Kh_hi + (size_t)(key0n + key) * DMODEL;
            const __bf16* sl = Kh_lo + (size_t)(key0n + key) * DMODEL;
            pk0 = *(const uint4*)(sk + c1 * 8); pk1 = *(const uint4*)(sk + c1 * 8 + 32);
            pl0 = *(const uint4*)(sl + c1 * 8); pl1 = *(const uint4*)(sl + c1 * 8 + 32);
            pv0 = *(const uint4*)(vrow + key0n + c1 * 8);
            pv1 = *(const uint4*)(vrow + key0n + c1 * 8 + 32);
        }

        // ---- S(log2 domain) = Q K^T, split-bf16: hi.hi + hi.lo + lo.hi
        f32x4 sc[4] = {};
        __builtin_amdgcn_s_setprio(1);
#pragma unroll
        for (int ni = 0; ni < 4; ni++) {
            bf16x8 kh0 = *(const bf16x8*)&KhF[(ni * 64 + lane) * 8];
            bf16x8 kh1 = *(const bf16x8*)&KhF[((4 + ni) * 64 + lane) * 8];
            bf16x8 kl0 = *(const bf16x8*)&KlF[(ni * 64 + lane) * 8];
            bf16x8 kl1 = *(const bf16x8*)&KlF[((4 + ni) * 64 + lane) * 8];
            sc[ni] = __builtin_amdgcn_mfma_f32_16x16x32_bf16(aqh0, kh0, sc[ni], 0, 0, 0);
            sc[ni] = __builtin_amdgcn_mfma_f32_16x16x32_bf16(aqh1, kh1, sc[ni], 0, 0, 0);
            sc[ni] = __builtin_amdgcn_mfma_f32_16x16x32_bf16(aqh0, kl0, sc[ni], 0, 0, 0);
            sc[ni] = __builtin_amdgcn_mfma_f32_16x16x32_bf16(aqh1, kl1, sc[ni], 0, 0, 0);
            sc[ni] = __builtin_amdgcn_mfma_f32_16x16x32_bf16(aql0, kh0, sc[ni], 0, 0, 0);
            sc[ni] = __builtin_amdgcn_mfma_f32_16x16x32_bf16(aql1, kh1, sc[ni], 0, 0, 0);
        }
        __builtin_amdgcn_s_setprio(0);

        if (diag) {
#pragma unroll
            for (int ni = 0; ni < 4; ni++) {
                int keyi = key0 + ni * 16 + l15;
#pragma unroll
                for (int rg = 0; rg < 4; rg++)
                    if (keyi > qrb + rg) sc[ni][rg] = -1e30f;
            }
        }

        // ---- defer-max check: lane-local, no cross-lane ops
        float cm[4];
#pragma unroll
        for (int rg = 0; rg < 4; rg++) {
            float lm = fmaxf(fmaxf(sc[0][rg], sc[1][rg]),
                             fmaxf(sc[2][rg], sc[3][rg]));
            cm[rg] = lm - m[rg];
        }
        float cmax = fmaxf(fmaxf(cm[0], cm[1]), fmaxf(cm[2], cm[3]));

        if (__all(cmax <= 8.0f)) {
            // fast path (~85-90% of iters): keep old m, no rescale, no reduce
#pragma unroll
            for (int rg = 0; rg < 4; rg++)
#pragma unroll
                for (int ni = 0; ni < 4; ni++) {
                    float px = __builtin_amdgcn_exp2f(sc[ni][rg] - m[rg]);
                    Ps[wave][quad * 4 + rg][ni * 16 + l15] = (__bf16)px;
                }
        } else {
            // full online-softmax update
#pragma unroll
            for (int rg = 0; rg < 4; rg++) {
                float mx = fmaxf(fmaxf(sc[0][rg], sc[1][rg]),
                                 fmaxf(sc[2][rg], sc[3][rg]));
#pragma unroll
                for (int mm = 1; mm < 16; mm <<= 1)
                    mx = fmaxf(mx, __shfl_xor(mx, mm, 64));
                float mnew  = fmaxf(m[rg], mx);
                float alpha = __builtin_amdgcn_exp2f(m[rg] - mnew);
                m[rg] = mnew;
#pragma unroll
                for (int ni = 0; ni < 4; ni++) {
                    float px = __builtin_amdgcn_exp2f(sc[ni][rg] - mnew);
                    Ps[wave][quad * 4 + rg][ni * 16 + l15] = (__bf16)px;
                }
                ol[rg] *= alpha;
#pragma unroll
                for (int ni = 0; ni < 4; ni++)
                    o[ni][rg] *= alpha;
            }
        }

        __builtin_amdgcn_s_setprio(1);
#pragma unroll
        for (int step = 0; step < 2; step++) {
            bf16x8 ap = *(const bf16x8*)&Ps[wave][l15][step * 32 + quad * 8];
            ol = __builtin_amdgcn_mfma_f32_16x16x32_bf16(ap, ones, ol, 0, 0, 0);
#pragma unroll
            for (int ni = 0; ni < 4; ni++) {
                bf16x8 bv = *(const bf16x8*)&VF[((step * 4 + ni) * 64 + lane) * 8];
                o[ni] = __builtin_amdgcn_mfma_f32_16x16x32_bf16(ap, bv, o[ni], 0, 0, 0);
            }
        }
        __builtin_amdgcn_s_setprio(0);
    }

    if (!split) {
        // ---- epilogue: coalesced merged-layout store
#pragma unroll
        for (int rg = 0; rg < 4; rg++) {
            float inv = 1.0f / ol[rg];
            int q = q0w + quad * 4 + rg;
#pragma unroll
            for (int ni = 0; ni < 4; ni++) {
                attn[((size_t)b * S_LEN + q) * DMODEL + h * HDIM + ni * 16 + l15] =
                    (__bf16)(o[ni][rg] * inv);
            }
        }
    } else {
        // ---- partial epilogue: unnormalized f32 o + per-row (m, l)
        int pair = bh * 16 + (t - 16);                 // 0..511
        float* po = part ? po1 : po0;
        float* pm = pml + ((size_t)part * 512 + pair) * 128;
#pragma unroll
        for (int rg = 0; rg < 4; rg++) {
            int row = wave * 16 + quad * 4 + rg;       // 0..63
            if (l15 == 0) { pm[row] = m[rg]; pm[64 + row] = ol[rg]; }
#pragma unroll
            for (int ni = 0; ni < 4; ni++)
                po[((size_t)pair * 64 + row) * 64 + ni * 16 + l15] = o[ni][rg];
        }
    }
}

// ---------------------------------------------------------------------------
// Combine: merge the two KV-half partials of each long q-tile.
// Grid 512 (one block per (bh, t>=16) pair), 256 threads: 16 dims/thread.
// ---------------------------------------------------------------------------
__global__ __launch_bounds__(256) void combine(const float* __restrict__ po0,
                                               const float* __restrict__ po1,
                                               const float* __restrict__ pml,
                                               __bf16* __restrict__ attn) {
    int pair = blockIdx.x;                  // 0..511
    int bh = pair >> 4, t = 16 + (pair & 15);
    int b = bh >> 4, h = bh & 15;
    int tid = threadIdx.x;
    int row = tid >> 2, c = (tid & 3) * 16;

    const float* m0p = pml + (size_t)pair * 128;
    const float* m1p = pml + (size_t)512 * 128 + (size_t)pair * 128;
    float m0 = m0p[row], l0 = m0p[64 + row];
    float m1 = m1p[row], l1 = m1p[64 + row];
    float mm = fmaxf(m0, m1);
    float s0 = __builtin_amdgcn_exp2f(m0 - mm);
    float s1 = __builtin_amdgcn_exp2f(m1 - mm);
    float inv = 1.0f / (l0 * s0 + l1 * s1);

    const float* r0 = po0 + ((size_t)pair * 64 + row) * 64 + c;
    const float* r1 = po1 + ((size_t)pair * 64 + row) * 64 + c;
    int q = t * 64 + row;
    __bf16* dst = attn + ((size_t)b * S_LEN + q) * DMODEL + h * HDIM + c;
#pragma unroll
    for (int j = 0; j < 16; j += 4) {
        f32x4 a  = *(const f32x4*)(r0 + j);
        f32x4 bb = *(const f32x4*)(r1 + j);
#pragma unroll
        for (int e = 0; e < 4; e++)
            dst[j + e] = (__bf16)((a[e] * s0 + bb[e] * s1) * inv);
    }
}

// ---------------------------------------------------------------------------
extern "C" void kernel_launch(void* const* d_in, const int* in_sizes, int n_in,
                              void* d_out, int out_size, void* d_ws, size_t ws_size,
                              hipStream_t stream) {
    const float* x  = (const float*)d_in[0];
    const float* qw = (const float*)d_in[1];
    const float* kw = (const float*)d_in[2];
    const float* vw = (const float*)d_in[3];
    const float* ow = (const float*)d_in[4];

    char* ws = (char*)d_ws;
    const size_t MB = 1024 * 1024;
    __bf16* xhi   = (__bf16*)(ws);             //  8 MB  [4096,1024]
    __bf16* xlo   = (__bf16*)(ws + 8 * MB);    //  8 MB  (reused as attnb later)
    __bf16* qwthi = (__bf16*)(ws + 16 * MB);   //  2 MB each
    __bf16* qwtlo = (__bf16*)(ws + 18 * MB);
    __bf16* kwthi = (__bf16*)(ws + 20 * MB);
    __bf16* kwtlo = (__bf16*)(ws + 22 * MB);
    __bf16* vwt   = (__bf16*)(ws + 24 * MB);
    __bf16* owt   = (__bf16*)(ws + 26 * MB);
    __bf16* Qhi_b = (__bf16*)(ws + 28 * MB);   //  8 MB  merged [B*S][D]
    __bf16* Qlo_b = (__bf16*)(ws + 36 * MB);
    __bf16* Khi_b = (__bf16*)(ws + 44 * MB);
    __bf16* Klo_b = (__bf16*)(ws + 52 * MB);
    __bf16* Vtb   = (__bf16*)(ws + 60 * MB);   //  8 MB  [B,H,64,S]
    __bf16* attnb = xlo;                       //  alias: xlo dead after QKV GEMMs
    // Partial-o buffers live in regions dead once flash_attn runs:
    float* po0 = (float*)(ws);                 //  8 MB  over xhi      [512][64][64]
    float* po1 = (float*)(ws + 16 * MB);       //  8 MB  over qwt/kwt  [512][64][64]
    float* pml = (float*)(ws + 24 * MB);       // 512 KB over vwt      [2][512][128]

    prep_all<<<8192, 256, 0, stream>>>(x, qw, kw, vw, ow,
                                       xhi, xlo, qwthi, qwtlo, kwthi, kwtlo,
                                       vwt, owt);

    qkv_gemm<<<dim3(8, 32, 3), 256, 0, stream>>>(
        xhi, xlo, qwthi, qwtlo, kwthi, kwtlo, vwt,
        Qhi_b, Qlo_b, Khi_b, Klo_b, Vtb);

    flash_attn<<<1536, 256, 0, stream>>>(Qhi_b, Qlo_b, Khi_b, Klo_b, Vtb, attnb,
                                         po0, po1, pml);

    combine<<<512, 256, 0, stream>>>(po0, po1, pml, attnb);

    out_gemm<<<dim3(8, 64), 256, 0, stream>>>(attnb, owt, (float*)d_out);
}

// Round 3
// 259.948 us; speedup vs baseline: 1.0355x; 1.0355x over previous
//
#include <hip/hip_runtime.h>

// ---------------------------------------------------------------------------
// MultiHeadAttention: B=2, S=2048, D=1024, H=16, hd=64
// Interleaved head split: Q[b,h,s,d] = proj[b,s, d*16+h]; scale = 1/32.
// Precision: split-bf16 (hi+lo) emulated-fp32 for Q/K path. V/attn/out bf16.
// v12: flash_attn q-fattening. 128 q-rows/block (32/wave as 2 sub-tiles):
// K-frags read once per ni serve both q-halves (was: each wave re-read the
// whole K tile for only 16 rows -> 4x redundant, ~33% of LDS-pipe budget);
// V-frags likewise shared across q-halves. Per-work LDS demand -31%.
// Grid 512, complement-paired t so each CU's 2 blocks sum to 34 iters.
// defer-max / setprio / split-KV / combine (R0-R1 regressions) removed.
// ---------------------------------------------------------------------------

typedef __bf16 bf16x8 __attribute__((ext_vector_type(8)));
typedef float  f32x4  __attribute__((ext_vector_type(4)));

#define S_LEN  2048
#define DMODEL 1024
#define NHEADS 16
#define HDIM   64
#define LOG2E  1.44269504088896340736f

__device__ __forceinline__ void gll16(const __bf16* g, __bf16* l) {
    __builtin_amdgcn_global_load_lds(
        (const __attribute__((address_space(1))) unsigned int*)g,
        (__attribute__((address_space(3))) unsigned int*)l, 16, 0, 0);
}

// ---------------------------------------------------------------------------
// Fused prep: id<4096 -> f32->(hi,lo) conv of x; else weight transposes.
// z=0: qw split col-permuted; z=1: kw; z=2: vw plain; z=3: ow k-permuted.
// perm(i) = (i&15)*64 + (i>>4).
// ---------------------------------------------------------------------------
__global__ __launch_bounds__(256) void prep_all(
    const float* __restrict__ x,
    const float* __restrict__ qw, const float* __restrict__ kw,
    const float* __restrict__ vw, const float* __restrict__ ow,
    __bf16* __restrict__ xhi, __bf16* __restrict__ xlo,
    __bf16* __restrict__ qwthi, __bf16* __restrict__ qwtlo,
    __bf16* __restrict__ kwthi, __bf16* __restrict__ kwtlo,
    __bf16* __restrict__ vwt,  __bf16* __restrict__ owt) {
    __shared__ float tile[32][33];
    int id = blockIdx.x;
    if (id < 4096) {
        int i = id * 256 + threadIdx.x;
        float4 v = ((const float4*)x)[i];
        __bf16 h0 = (__bf16)v.x, h1 = (__bf16)v.y, h2 = (__bf16)v.z, h3 = (__bf16)v.w;
        ushort4 hh, ll;
        hh.x = __builtin_bit_cast(unsigned short, h0);
        hh.y = __builtin_bit_cast(unsigned short, h1);
        hh.z = __builtin_bit_cast(unsigned short, h2);
        hh.w = __builtin_bit_cast(unsigned short, h3);
        ll.x = __builtin_bit_cast(unsigned short, (__bf16)(v.x - (float)h0));
        ll.y = __builtin_bit_cast(unsigned short, (__bf16)(v.y - (float)h1));
        ll.z = __builtin_bit_cast(unsigned short, (__bf16)(v.z - (float)h2));
        ll.w = __builtin_bit_cast(unsigned short, (__bf16)(v.w - (float)h3));
        ((ushort4*)xhi)[i] = hh;
        ((ushort4*)xlo)[i] = ll;
        return;
    }
    int rid = id - 4096;
    int z = rid >> 10;                       // 0..3
    int bx = rid & 31, by = (rid >> 5) & 31;
    const float* w = (z == 0) ? qw : (z == 1) ? kw : (z == 2) ? vw : ow;
    int n0 = bx * 32, k0 = by * 32;
    int tx = threadIdx.x & 31, ty = threadIdx.x >> 5;
#pragma unroll
    for (int i = 0; i < 32; i += 8)
        tile[ty + i][tx] = w[(k0 + ty + i) * DMODEL + n0 + tx];
    __syncthreads();
#pragma unroll
    for (int i = 0; i < 32; i += 8) {
        float f = tile[tx][ty + i];           // = w[k0+tx][n0+ty+i]
        int k = k0 + tx, n = n0 + ty + i;
        if (z <= 1) {
            __bf16 fh = (__bf16)f;
            __bf16 fl = (__bf16)(f - (float)fh);
            int c = (n & 15) * 64 + (n >> 4);
            if (z == 0) { qwthi[c * DMODEL + k] = fh; qwtlo[c * DMODEL + k] = fl; }
            else        { kwthi[c * DMODEL + k] = fh; kwtlo[c * DMODEL + k] = fl; }
        } else if (z == 2) {
            vwt[n * DMODEL + k] = (__bf16)f;
        } else {
            int ck = (k & 15) * 64 + (k >> 4);
            owt[n * DMODEL + ck] = (__bf16)f;
        }
    }
}

// ---------------------------------------------------------------------------
// QKV projections. grid (8, 32, 3), LDS chunk-swizzled (2-way frag reads).
// z=0: Q = x @ qw (split-bf16, scale log2e/32), merged [m][c] hi/lo out.
// z=1: K likewise, scale 1.
// z=2: V^T = vwt @ x^T (plain), out [bh][d][s].
// ---------------------------------------------------------------------------
__global__ __launch_bounds__(256) void qkv_gemm(
    const __bf16* __restrict__ xhi, const __bf16* __restrict__ xlo,
    const __bf16* __restrict__ qwthi, const __bf16* __restrict__ qwtlo,
    const __bf16* __restrict__ kwthi, const __bf16* __restrict__ kwtlo,
    const __bf16* __restrict__ vwt,
    __bf16* __restrict__ Qhi, __bf16* __restrict__ Qlo,
    __bf16* __restrict__ Khi, __bf16* __restrict__ Klo,
    __bf16* __restrict__ Vt) {
    __shared__ __bf16 Ash[128][32], Asl[128][32], Bsh[128][32], Bsl[128][32];
    int mode = blockIdx.z;
    int tid  = threadIdx.x;
    int wave = tid >> 6, lane = tid & 63;
    int quad = lane >> 4, l15 = lane & 15;
    int wm = (wave >> 1) * 64, wn = (wave & 1) * 64;
    int grow = lane >> 2;
    int gcol = (((lane & 3) - ((lane >> 3) & 3)) & 3) * 8;   // swizzled source chunk
    int sA   = ((quad + (l15 >> 1)) & 3) * 8;                // swizzled frag slot
    const int K = DMODEL;

    if (mode < 2) {
        const __bf16* Bh = mode ? kwthi : qwthi;
        const __bf16* Bl = mode ? kwtlo : qwtlo;
        int m0 = blockIdx.y * 128, n0 = blockIdx.x * 128;
        f32x4 acc[4][4] = {};
        for (int k0 = 0; k0 < K; k0 += 32) {
            __syncthreads();
#pragma unroll
            for (int ps = 0; ps < 2; ps++) {
                int row = ps * 64 + wave * 16;
                gll16(&xhi[(m0 + row + grow) * K + k0 + gcol], &Ash[row][0]);
                gll16(&xlo[(m0 + row + grow) * K + k0 + gcol], &Asl[row][0]);
                gll16(&Bh [(n0 + row + grow) * K + k0 + gcol], &Bsh[row][0]);
                gll16(&Bl [(n0 + row + grow) * K + k0 + gcol], &Bsl[row][0]);
            }
            __syncthreads();
            bf16x8 ah[4], al[4], bh[4], bl[4];
#pragma unroll
            for (int mi = 0; mi < 4; mi++) {
                ah[mi] = *(const bf16x8*)&Ash[wm + mi * 16 + l15][sA];
                al[mi] = *(const bf16x8*)&Asl[wm + mi * 16 + l15][sA];
            }
#pragma unroll
            for (int ni = 0; ni < 4; ni++) {
                bh[ni] = *(const bf16x8*)&Bsh[wn + ni * 16 + l15][sA];
                bl[ni] = *(const bf16x8*)&Bsl[wn + ni * 16 + l15][sA];
            }
#pragma unroll
            for (int mi = 0; mi < 4; mi++)
#pragma unroll
                for (int ni = 0; ni < 4; ni++) {
                    acc[mi][ni] = __builtin_amdgcn_mfma_f32_16x16x32_bf16(ah[mi], bh[ni], acc[mi][ni], 0, 0, 0);
                    acc[mi][ni] = __builtin_amdgcn_mfma_f32_16x16x32_bf16(ah[mi], bl[ni], acc[mi][ni], 0, 0, 0);
                    acc[mi][ni] = __builtin_amdgcn_mfma_f32_16x16x32_bf16(al[mi], bh[ni], acc[mi][ni], 0, 0, 0);
                }
        }
        float oscale = mode ? 1.0f : 0.03125f * LOG2E;
        __bf16* Ohi = mode ? Khi : Qhi;
        __bf16* Olo = mode ? Klo : Qlo;
#pragma unroll
        for (int mi = 0; mi < 4; mi++)
#pragma unroll
            for (int ni = 0; ni < 4; ni++)
#pragma unroll
                for (int rg = 0; rg < 4; rg++) {
                    int m = m0 + wm + mi * 16 + quad * 4 + rg;
                    int n = n0 + wn + ni * 16 + l15;     // n == merged channel
                    float v = acc[mi][ni][rg] * oscale;
                    size_t idx = (size_t)m * DMODEL + n;
                    __bf16 vh = (__bf16)v;
                    Ohi[idx] = vh;
                    Olo[idx] = (__bf16)(v - (float)vh);
                }
    } else {
        // V^T: A = vwt (channel rows), B = xhi (x rows); C[ch][xm]
        int ch0 = blockIdx.x * 128, xm0 = blockIdx.y * 128;
        f32x4 acc[4][4] = {};
        for (int k0 = 0; k0 < K; k0 += 32) {
            __syncthreads();
#pragma unroll
            for (int ps = 0; ps < 2; ps++) {
                int row = ps * 64 + wave * 16;
                gll16(&vwt[(ch0 + row + grow) * K + k0 + gcol], &Ash[row][0]);
                gll16(&xhi[(xm0 + row + grow) * K + k0 + gcol], &Bsh[row][0]);
            }
            __syncthreads();
            bf16x8 af[4], bfr[4];
#pragma unroll
            for (int mi = 0; mi < 4; mi++)
                af[mi] = *(const bf16x8*)&Ash[wm + mi * 16 + l15][sA];
#pragma unroll
            for (int ni = 0; ni < 4; ni++)
                bfr[ni] = *(const bf16x8*)&Bsh[wn + ni * 16 + l15][sA];
#pragma unroll
            for (int mi = 0; mi < 4; mi++)
#pragma unroll
                for (int ni = 0; ni < 4; ni++)
                    acc[mi][ni] = __builtin_amdgcn_mfma_f32_16x16x32_bf16(
                        af[mi], bfr[ni], acc[mi][ni], 0, 0, 0);
        }
#pragma unroll
        for (int mi = 0; mi < 4; mi++)
#pragma unroll
            for (int ni = 0; ni < 4; ni++)
#pragma unroll
                for (int rg = 0; rg < 4; rg++) {
                    int ch = ch0 + wm + mi * 16 + quad * 4 + rg;
                    int xm = xm0 + wn + ni * 16 + l15;
                    int b = xm >> 11, s = xm & 2047;
                    int h = ch & 15,  d = ch >> 4;
                    Vt[((size_t)(b * NHEADS + h) * HDIM + d) * S_LEN + s] =
                        (__bf16)acc[mi][ni][rg];
                }
    }
}

// ---------------------------------------------------------------------------
// Output projection: out[m][n] = attnb[m][:] . owt[n][:], fp32 out.
// 64x128 tiles -> grid (8,64) = 512 blocks. Swizzled LDS.
// ---------------------------------------------------------------------------
__global__ __launch_bounds__(256) void out_gemm(const __bf16* __restrict__ A,
                                                const __bf16* __restrict__ Bt,
                                                float* __restrict__ out) {
    __shared__ __bf16 As[64][32];
    __shared__ __bf16 Bs[128][32];
    int tid  = threadIdx.x;
    int wave = tid >> 6, lane = tid & 63;
    int quad = lane >> 4, l15 = lane & 15;
    int m0 = blockIdx.y * 64, n0 = blockIdx.x * 128;
    int wm = (wave >> 1) * 32, wn = (wave & 1) * 64;
    int grow = lane >> 2;
    int gcol = (((lane & 3) - ((lane >> 3) & 3)) & 3) * 8;
    int sA   = ((quad + (l15 >> 1)) & 3) * 8;
    const int K = DMODEL;
    f32x4 acc[2][4] = {};

    for (int k0 = 0; k0 < K; k0 += 32) {
        __syncthreads();
        gll16(&A[(m0 + wave * 16 + grow) * K + k0 + gcol], &As[wave * 16][0]);
#pragma unroll
        for (int ps = 0; ps < 2; ps++) {
            int row = ps * 64 + wave * 16;
            gll16(&Bt[(n0 + row + grow) * K + k0 + gcol], &Bs[row][0]);
        }
        __syncthreads();
        bf16x8 af[2], bfr[4];
#pragma unroll
        for (int mi = 0; mi < 2; mi++)
            af[mi] = *(const bf16x8*)&As[wm + mi * 16 + l15][sA];
#pragma unroll
        for (int ni = 0; ni < 4; ni++)
            bfr[ni] = *(const bf16x8*)&Bs[wn + ni * 16 + l15][sA];
#pragma unroll
        for (int mi = 0; mi < 2; mi++)
#pragma unroll
            for (int ni = 0; ni < 4; ni++)
                acc[mi][ni] = __builtin_amdgcn_mfma_f32_16x16x32_bf16(
                    af[mi], bfr[ni], acc[mi][ni], 0, 0, 0);
    }

#pragma unroll
    for (int mi = 0; mi < 2; mi++)
#pragma unroll
        for (int ni = 0; ni < 4; ni++)
#pragma unroll
            for (int rg = 0; rg < 4; rg++) {
                int m = m0 + wm + mi * 16 + quad * 4 + rg;
                int n = n0 + wn + ni * 16 + l15;
                out[(size_t)m * DMODEL + n] = acc[mi][ni][rg];
            }
}

// ---------------------------------------------------------------------------
// Flash attention (v12): 128 q-rows per block, 32 per wave (2 sub-tiles).
// K/V fragments read from LDS once per ni/step serve BOTH q-halves.
// Grid 512 = 32 bh x 16 q-tiles; ids 0..255 carry t=15..8, ids 256..511
// carry t=0..7, so a CU's pair (c, c+256) sums to a constant 34 iters.
// ---------------------------------------------------------------------------
__global__ __launch_bounds__(256, 2) void flash_attn(const __bf16* __restrict__ Qhi,
                                                     const __bf16* __restrict__ Qlo,
                                                     const __bf16* __restrict__ Khi,
                                                     const __bf16* __restrict__ Klo,
                                                     const __bf16* __restrict__ Vt,
                                                     __bf16* __restrict__ attn) {
    int id  = blockIdx.x;
    int xcd = id & 7, r = id >> 3;          // r 0..63
    int bh  = xcd + 8 * (r & 3);            // 4 heads pinned per XCD
    int rr  = r >> 2;                       // 0..15
    int t   = (rr < 8) ? (15 - rr) : (rr - 8);   // complement pairing
    int b = bh >> 4, h = bh & 15;
    const __bf16* Qh_hi = Qhi + (size_t)b * S_LEN * DMODEL + h * HDIM;
    const __bf16* Qh_lo = Qlo + (size_t)b * S_LEN * DMODEL + h * HDIM;
    const __bf16* Kh_hi = Khi + (size_t)b * S_LEN * DMODEL + h * HDIM;
    const __bf16* Kh_lo = Klo + (size_t)b * S_LEN * DMODEL + h * HDIM;
    const __bf16* Vh    = Vt  + (size_t)bh * HDIM * S_LEN;

    int tid = threadIdx.x, wave = tid >> 6, lane = tid & 63;
    int quad = lane >> 4, l15 = lane & 15;
    int iters = 2 * t + 2;

    __shared__ __bf16 KhF[8 * 64 * 8];
    __shared__ __bf16 KlF[8 * 64 * 8];
    __shared__ __bf16 VF [8 * 64 * 8];
    __shared__ __bf16 Ps[4][32][72];

    int c1  = tid >> 6, key = tid & 63;
    int inner = (c1 * 16 + (key & 15)) * 8;
    int rK    = (key >> 4);
    int kdst0 = rK * 512 + inner, kdst1 = (4 + rK) * 512 + inner;
    const __bf16* vrow = Vh + (size_t)key * S_LEN;   // dim = key var

    int qbase = t * 128 + wave * 32;        // this wave's 32 q-rows
    bf16x8 aqh0[2], aqh1[2], aql0[2], aql1[2];
#pragma unroll
    for (int qh = 0; qh < 2; qh++) {
        size_t qr = (size_t)(qbase + qh * 16 + l15) * DMODEL;
        aqh0[qh] = *(const bf16x8*)&Qh_hi[qr + quad * 8];
        aqh1[qh] = *(const bf16x8*)&Qh_hi[qr + 32 + quad * 8];
        aql0[qh] = *(const bf16x8*)&Qh_lo[qr + quad * 8];
        aql1[qh] = *(const bf16x8*)&Qh_lo[qr + 32 + quad * 8];
    }

    bf16x8 ones;
#pragma unroll
    for (int j = 0; j < 8; j++) ones[j] = (__bf16)1.0f;

    uint4 pk0, pk1, pl0, pl1, pv0, pv1;
    {   // prefetch tile 0
        const __bf16* sk = Kh_hi + (size_t)key * DMODEL;
        const __bf16* sl = Kh_lo + (size_t)key * DMODEL;
        pk0 = *(const uint4*)(sk + c1 * 8); pk1 = *(const uint4*)(sk + c1 * 8 + 32);
        pl0 = *(const uint4*)(sl + c1 * 8); pl1 = *(const uint4*)(sl + c1 * 8 + 32);
        pv0 = *(const uint4*)(vrow + c1 * 8); pv1 = *(const uint4*)(vrow + c1 * 8 + 32);
    }

    float m[2][4] = {{-3e38f, -3e38f, -3e38f, -3e38f},
                     {-3e38f, -3e38f, -3e38f, -3e38f}};
    f32x4 o[2][4] = {};
    f32x4 ol[2] = {};

    for (int i = 0; i < iters; i++) {
        int key0 = i * 64;

        __syncthreads();
        *(uint4*)&KhF[kdst0] = pk0;  *(uint4*)&KhF[kdst1] = pk1;
        *(uint4*)&KlF[kdst0] = pl0;  *(uint4*)&KlF[kdst1] = pl1;
        *(uint4*)&VF [kdst0] = pv0;  *(uint4*)&VF [kdst1] = pv1;
        __syncthreads();

        if (i + 1 < iters) {
            int key0n = (i + 1) * 64;
            const __bf16* sk = Kh_hi + (size_t)(key0n + key) * DMODEL;
            const __bf16* sl = Kh_lo + (size_t)(key0n + key) * DMODEL;
            pk0 = *(const uint4*)(sk + c1 * 8); pk1 = *(const uint4*)(sk + c1 * 8 + 32);
            pl0 = *(const uint4*)(sl + c1 * 8); pl1 = *(const uint4*)(sl + c1 * 8 + 32);
            pv0 = *(const uint4*)(vrow + key0n + c1 * 8);
            pv1 = *(const uint4*)(vrow + key0n + c1 * 8 + 32);
        }

        // waves whose whole 32-row q-range is below this key-tile skip compute
        if (key0 > qbase + 31) continue;

        // ---- S(log2 domain) = Q K^T, split-bf16: hi.hi + hi.lo + lo.hi
        // K-frags read ONCE per ni, feed both q-halves.
        f32x4 sc[2][4] = {};
#pragma unroll
        for (int ni = 0; ni < 4; ni++) {
            bf16x8 kh0 = *(const bf16x8*)&KhF[(ni * 64 + lane) * 8];
            bf16x8 kh1 = *(const bf16x8*)&KhF[((4 + ni) * 64 + lane) * 8];
            bf16x8 kl0 = *(const bf16x8*)&KlF[(ni * 64 + lane) * 8];
            bf16x8 kl1 = *(const bf16x8*)&KlF[((4 + ni) * 64 + lane) * 8];
#pragma unroll
            for (int qh = 0; qh < 2; qh++) {
                sc[qh][ni] = __builtin_amdgcn_mfma_f32_16x16x32_bf16(aqh0[qh], kh0, sc[qh][ni], 0, 0, 0);
                sc[qh][ni] = __builtin_amdgcn_mfma_f32_16x16x32_bf16(aqh1[qh], kh1, sc[qh][ni], 0, 0, 0);
                sc[qh][ni] = __builtin_amdgcn_mfma_f32_16x16x32_bf16(aqh0[qh], kl0, sc[qh][ni], 0, 0, 0);
                sc[qh][ni] = __builtin_amdgcn_mfma_f32_16x16x32_bf16(aqh1[qh], kl1, sc[qh][ni], 0, 0, 0);
                sc[qh][ni] = __builtin_amdgcn_mfma_f32_16x16x32_bf16(aql0[qh], kh0, sc[qh][ni], 0, 0, 0);
                sc[qh][ni] = __builtin_amdgcn_mfma_f32_16x16x32_bf16(aql1[qh], kh1, sc[qh][ni], 0, 0, 0);
            }
        }

        if (i >= 2 * t) {                   // diagonal band: causal mask
#pragma unroll
            for (int qh = 0; qh < 2; qh++) {
                int qrb = qbase + qh * 16 + quad * 4;
#pragma unroll
                for (int ni = 0; ni < 4; ni++) {
                    int keyi = key0 + ni * 16 + l15;
#pragma unroll
                    for (int rg = 0; rg < 4; rg++)
                        if (keyi > qrb + rg) sc[qh][ni][rg] = -1e30f;
                }
            }
        }

        // ---- online softmax per q-half (v6-proven sequence)
#pragma unroll
        for (int qh = 0; qh < 2; qh++) {
#pragma unroll
            for (int rg = 0; rg < 4; rg++) {
                float mx = fmaxf(fmaxf(sc[qh][0][rg], sc[qh][1][rg]),
                                 fmaxf(sc[qh][2][rg], sc[qh][3][rg]));
#pragma unroll
                for (int mm = 1; mm < 16; mm <<= 1)
                    mx = fmaxf(mx, __shfl_xor(mx, mm, 64));
                float mnew  = fmaxf(m[qh][rg], mx);
                float alpha = __builtin_amdgcn_exp2f(m[qh][rg] - mnew);
                m[qh][rg] = mnew;
#pragma unroll
                for (int ni = 0; ni < 4; ni++) {
                    float px = __builtin_amdgcn_exp2f(sc[qh][ni][rg] - mnew);
                    Ps[wave][qh * 16 + quad * 4 + rg][ni * 16 + l15] = (__bf16)px;
                }
                ol[qh][rg] *= alpha;
#pragma unroll
                for (int ni = 0; ni < 4; ni++)
                    o[qh][ni][rg] *= alpha;
            }
        }

        // ---- PV: V-frags read once per (step,ni), feed both q-halves
#pragma unroll
        for (int step = 0; step < 2; step++) {
            bf16x8 ap0 = *(const bf16x8*)&Ps[wave][l15][step * 32 + quad * 8];
            bf16x8 ap1 = *(const bf16x8*)&Ps[wave][16 + l15][step * 32 + quad * 8];
            ol[0] = __builtin_amdgcn_mfma_f32_16x16x32_bf16(ap0, ones, ol[0], 0, 0, 0);
            ol[1] = __builtin_amdgcn_mfma_f32_16x16x32_bf16(ap1, ones, ol[1], 0, 0, 0);
#pragma unroll
            for (int ni = 0; ni < 4; ni++) {
                bf16x8 bv = *(const bf16x8*)&VF[((step * 4 + ni) * 64 + lane) * 8];
                o[0][ni] = __builtin_amdgcn_mfma_f32_16x16x32_bf16(ap0, bv, o[0][ni], 0, 0, 0);
                o[1][ni] = __builtin_amdgcn_mfma_f32_16x16x32_bf16(ap1, bv, o[1][ni], 0, 0, 0);
            }
        }
    }

    // ---- epilogue: coalesced merged-layout store
#pragma unroll
    for (int qh = 0; qh < 2; qh++)
#pragma unroll
        for (int rg = 0; rg < 4; rg++) {
            float inv = 1.0f / ol[qh][rg];
            int q = qbase + qh * 16 + quad * 4 + rg;
#pragma unroll
            for (int ni = 0; ni < 4; ni++) {
                attn[((size_t)b * S_LEN + q) * DMODEL + h * HDIM + ni * 16 + l15] =
                    (__bf16)(o[qh][ni][rg] * inv);
            }
        }
}

// ---------------------------------------------------------------------------
extern "C" void kernel_launch(void* const* d_in, const int* in_sizes, int n_in,
                              void* d_out, int out_size, void* d_ws, size_t ws_size,
                              hipStream_t stream) {
    const float* x  = (const float*)d_in[0];
    const float* qw = (const float*)d_in[1];
    const float* kw = (const float*)d_in[2];
    const float* vw = (const float*)d_in[3];
    const float* ow = (const float*)d_in[4];

    char* ws = (char*)d_ws;
    const size_t MB = 1024 * 1024;
    __bf16* xhi   = (__bf16*)(ws);             //  8 MB  [4096,1024]
    __bf16* xlo   = (__bf16*)(ws + 8 * MB);    //  8 MB  (reused as attnb later)
    __bf16* qwthi = (__bf16*)(ws + 16 * MB);   //  2 MB each
    __bf16* qwtlo = (__bf16*)(ws + 18 * MB);
    __bf16* kwthi = (__bf16*)(ws + 20 * MB);
    __bf16* kwtlo = (__bf16*)(ws + 22 * MB);
    __bf16* vwt   = (__bf16*)(ws + 24 * MB);
    __bf16* owt   = (__bf16*)(ws + 26 * MB);
    __bf16* Qhi_b = (__bf16*)(ws + 28 * MB);   //  8 MB  merged [B*S][D]
    __bf16* Qlo_b = (__bf16*)(ws + 36 * MB);
    __bf16* Khi_b = (__bf16*)(ws + 44 * MB);
    __bf16* Klo_b = (__bf16*)(ws + 52 * MB);
    __bf16* Vtb   = (__bf16*)(ws + 60 * MB);   //  8 MB  [B,H,64,S]
    __bf16* attnb = xlo;                       //  alias: xlo dead after QKV GEMMs

    prep_all<<<8192, 256, 0, stream>>>(x, qw, kw, vw, ow,
                                       xhi, xlo, qwthi, qwtlo, kwthi, kwtlo,
                                       vwt, owt);

    qkv_gemm<<<dim3(8, 32, 3), 256, 0, stream>>>(
        xhi, xlo, qwthi, qwtlo, kwthi, kwtlo, vwt,
        Qhi_b, Qlo_b, Khi_b, Klo_b, Vtb);

    flash_attn<<<512, 256, 0, stream>>>(Qhi_b, Qlo_b, Khi_b, Klo_b, Vtb, attnb);

    out_gemm<<<dim3(8, 64), 256, 0, stream>>>(attnb, owt, (float*)d_out);
}

// Round 4
// 258.061 us; speedup vs baseline: 1.0431x; 1.0073x over previous
//
#include <hip/hip_runtime.h>

// ---------------------------------------------------------------------------
// MultiHeadAttention: B=2, S=2048, D=1024, H=16, hd=64
// Interleaved head split: Q[b,h,s,d] = proj[b,s, d*16+h]; scale = 1/32.
// Precision: split-bf16 (hi+lo) emulated-fp32 for Q/K path. V/attn/out bf16.
// v13: v12's q-fat loop (128 q-rows/block, K/V frag reads shared across 2
// q-halves, ~2.8x less LDS demand per work) + residency fix: every q-tile's
// KV range split into two equal (t+1)-iter halves -> 1024 blocks, 3/CU
// resident (LDS 43KB, launch_bounds(256,3)), longest-first. All blocks emit
// bf16 partials (o) + f32 (m,l) into dead ws regions; combine merges.
// v6 per-CU model: LDS-pipe saturated at 2256cyc/64-row-iter; v12 cut to
// ~790 but starved at 1 block/CU. v13 = efficient loop, saturated pipe.
// ---------------------------------------------------------------------------

typedef __bf16 bf16x8 __attribute__((ext_vector_type(8)));
typedef float  f32x4  __attribute__((ext_vector_type(4)));

#define S_LEN  2048
#define DMODEL 1024
#define NHEADS 16
#define HDIM   64
#define LOG2E  1.44269504088896340736f

__device__ __forceinline__ void gll16(const __bf16* g, __bf16* l) {
    __builtin_amdgcn_global_load_lds(
        (const __attribute__((address_space(1))) unsigned int*)g,
        (__attribute__((address_space(3))) unsigned int*)l, 16, 0, 0);
}

// ---------------------------------------------------------------------------
// Fused prep: id<4096 -> f32->(hi,lo) conv of x; else weight transposes.
// z=0: qw split col-permuted; z=1: kw; z=2: vw plain; z=3: ow k-permuted.
// perm(i) = (i&15)*64 + (i>>4).
// ---------------------------------------------------------------------------
__global__ __launch_bounds__(256) void prep_all(
    const float* __restrict__ x,
    const float* __restrict__ qw, const float* __restrict__ kw,
    const float* __restrict__ vw, const float* __restrict__ ow,
    __bf16* __restrict__ xhi, __bf16* __restrict__ xlo,
    __bf16* __restrict__ qwthi, __bf16* __restrict__ qwtlo,
    __bf16* __restrict__ kwthi, __bf16* __restrict__ kwtlo,
    __bf16* __restrict__ vwt,  __bf16* __restrict__ owt) {
    __shared__ float tile[32][33];
    int id = blockIdx.x;
    if (id < 4096) {
        int i = id * 256 + threadIdx.x;
        float4 v = ((const float4*)x)[i];
        __bf16 h0 = (__bf16)v.x, h1 = (__bf16)v.y, h2 = (__bf16)v.z, h3 = (__bf16)v.w;
        ushort4 hh, ll;
        hh.x = __builtin_bit_cast(unsigned short, h0);
        hh.y = __builtin_bit_cast(unsigned short, h1);
        hh.z = __builtin_bit_cast(unsigned short, h2);
        hh.w = __builtin_bit_cast(unsigned short, h3);
        ll.x = __builtin_bit_cast(unsigned short, (__bf16)(v.x - (float)h0));
        ll.y = __builtin_bit_cast(unsigned short, (__bf16)(v.y - (float)h1));
        ll.z = __builtin_bit_cast(unsigned short, (__bf16)(v.z - (float)h2));
        ll.w = __builtin_bit_cast(unsigned short, (__bf16)(v.w - (float)h3));
        ((ushort4*)xhi)[i] = hh;
        ((ushort4*)xlo)[i] = ll;
        return;
    }
    int rid = id - 4096;
    int z = rid >> 10;                       // 0..3
    int bx = rid & 31, by = (rid >> 5) & 31;
    const float* w = (z == 0) ? qw : (z == 1) ? kw : (z == 2) ? vw : ow;
    int n0 = bx * 32, k0 = by * 32;
    int tx = threadIdx.x & 31, ty = threadIdx.x >> 5;
#pragma unroll
    for (int i = 0; i < 32; i += 8)
        tile[ty + i][tx] = w[(k0 + ty + i) * DMODEL + n0 + tx];
    __syncthreads();
#pragma unroll
    for (int i = 0; i < 32; i += 8) {
        float f = tile[tx][ty + i];           // = w[k0+tx][n0+ty+i]
        int k = k0 + tx, n = n0 + ty + i;
        if (z <= 1) {
            __bf16 fh = (__bf16)f;
            __bf16 fl = (__bf16)(f - (float)fh);
            int c = (n & 15) * 64 + (n >> 4);
            if (z == 0) { qwthi[c * DMODEL + k] = fh; qwtlo[c * DMODEL + k] = fl; }
            else        { kwthi[c * DMODEL + k] = fh; kwtlo[c * DMODEL + k] = fl; }
        } else if (z == 2) {
            vwt[n * DMODEL + k] = (__bf16)f;
        } else {
            int ck = (k & 15) * 64 + (k >> 4);
            owt[n * DMODEL + ck] = (__bf16)f;
        }
    }
}

// ---------------------------------------------------------------------------
// QKV projections. grid (8, 32, 3), LDS chunk-swizzled (2-way frag reads).
// z=0: Q = x @ qw (split-bf16, scale log2e/32), merged [m][c] hi/lo out.
// z=1: K likewise, scale 1.
// z=2: V^T = vwt @ x^T (plain), out [bh][d][s].
// ---------------------------------------------------------------------------
__global__ __launch_bounds__(256) void qkv_gemm(
    const __bf16* __restrict__ xhi, const __bf16* __restrict__ xlo,
    const __bf16* __restrict__ qwthi, const __bf16* __restrict__ qwtlo,
    const __bf16* __restrict__ kwthi, const __bf16* __restrict__ kwtlo,
    const __bf16* __restrict__ vwt,
    __bf16* __restrict__ Qhi, __bf16* __restrict__ Qlo,
    __bf16* __restrict__ Khi, __bf16* __restrict__ Klo,
    __bf16* __restrict__ Vt) {
    __shared__ __bf16 Ash[128][32], Asl[128][32], Bsh[128][32], Bsl[128][32];
    int mode = blockIdx.z;
    int tid  = threadIdx.x;
    int wave = tid >> 6, lane = tid & 63;
    int quad = lane >> 4, l15 = lane & 15;
    int wm = (wave >> 1) * 64, wn = (wave & 1) * 64;
    int grow = lane >> 2;
    int gcol = (((lane & 3) - ((lane >> 3) & 3)) & 3) * 8;   // swizzled source chunk
    int sA   = ((quad + (l15 >> 1)) & 3) * 8;                // swizzled frag slot
    const int K = DMODEL;

    if (mode < 2) {
        const __bf16* Bh = mode ? kwthi : qwthi;
        const __bf16* Bl = mode ? kwtlo : qwtlo;
        int m0 = blockIdx.y * 128, n0 = blockIdx.x * 128;
        f32x4 acc[4][4] = {};
        for (int k0 = 0; k0 < K; k0 += 32) {
            __syncthreads();
#pragma unroll
            for (int ps = 0; ps < 2; ps++) {
                int row = ps * 64 + wave * 16;
                gll16(&xhi[(m0 + row + grow) * K + k0 + gcol], &Ash[row][0]);
                gll16(&xlo[(m0 + row + grow) * K + k0 + gcol], &Asl[row][0]);
                gll16(&Bh [(n0 + row + grow) * K + k0 + gcol], &Bsh[row][0]);
                gll16(&Bl [(n0 + row + grow) * K + k0 + gcol], &Bsl[row][0]);
            }
            __syncthreads();
            bf16x8 ah[4], al[4], bh[4], bl[4];
#pragma unroll
            for (int mi = 0; mi < 4; mi++) {
                ah[mi] = *(const bf16x8*)&Ash[wm + mi * 16 + l15][sA];
                al[mi] = *(const bf16x8*)&Asl[wm + mi * 16 + l15][sA];
            }
#pragma unroll
            for (int ni = 0; ni < 4; ni++) {
                bh[ni] = *(const bf16x8*)&Bsh[wn + ni * 16 + l15][sA];
                bl[ni] = *(const bf16x8*)&Bsl[wn + ni * 16 + l15][sA];
            }
#pragma unroll
            for (int mi = 0; mi < 4; mi++)
#pragma unroll
                for (int ni = 0; ni < 4; ni++) {
                    acc[mi][ni] = __builtin_amdgcn_mfma_f32_16x16x32_bf16(ah[mi], bh[ni], acc[mi][ni], 0, 0, 0);
                    acc[mi][ni] = __builtin_amdgcn_mfma_f32_16x16x32_bf16(ah[mi], bl[ni], acc[mi][ni], 0, 0, 0);
                    acc[mi][ni] = __builtin_amdgcn_mfma_f32_16x16x32_bf16(al[mi], bh[ni], acc[mi][ni], 0, 0, 0);
                }
        }
        float oscale = mode ? 1.0f : 0.03125f * LOG2E;
        __bf16* Ohi = mode ? Khi : Qhi;
        __bf16* Olo = mode ? Klo : Qlo;
#pragma unroll
        for (int mi = 0; mi < 4; mi++)
#pragma unroll
            for (int ni = 0; ni < 4; ni++)
#pragma unroll
                for (int rg = 0; rg < 4; rg++) {
                    int m = m0 + wm + mi * 16 + quad * 4 + rg;
                    int n = n0 + wn + ni * 16 + l15;     // n == merged channel
                    float v = acc[mi][ni][rg] * oscale;
                    size_t idx = (size_t)m * DMODEL + n;
                    __bf16 vh = (__bf16)v;
                    Ohi[idx] = vh;
                    Olo[idx] = (__bf16)(v - (float)vh);
                }
    } else {
        // V^T: A = vwt (channel rows), B = xhi (x rows); C[ch][xm]
        int ch0 = blockIdx.x * 128, xm0 = blockIdx.y * 128;
        f32x4 acc[4][4] = {};
        for (int k0 = 0; k0 < K; k0 += 32) {
            __syncthreads();
#pragma unroll
            for (int ps = 0; ps < 2; ps++) {
                int row = ps * 64 + wave * 16;
                gll16(&vwt[(ch0 + row + grow) * K + k0 + gcol], &Ash[row][0]);
                gll16(&xhi[(xm0 + row + grow) * K + k0 + gcol], &Bsh[row][0]);
            }
            __syncthreads();
            bf16x8 af[4], bfr[4];
#pragma unroll
            for (int mi = 0; mi < 4; mi++)
                af[mi] = *(const bf16x8*)&Ash[wm + mi * 16 + l15][sA];
#pragma unroll
            for (int ni = 0; ni < 4; ni++)
                bfr[ni] = *(const bf16x8*)&Bsh[wn + ni * 16 + l15][sA];
#pragma unroll
            for (int mi = 0; mi < 4; mi++)
#pragma unroll
                for (int ni = 0; ni < 4; ni++)
                    acc[mi][ni] = __builtin_amdgcn_mfma_f32_16x16x32_bf16(
                        af[mi], bfr[ni], acc[mi][ni], 0, 0, 0);
        }
#pragma unroll
        for (int mi = 0; mi < 4; mi++)
#pragma unroll
            for (int ni = 0; ni < 4; ni++)
#pragma unroll
                for (int rg = 0; rg < 4; rg++) {
                    int ch = ch0 + wm + mi * 16 + quad * 4 + rg;
                    int xm = xm0 + wn + ni * 16 + l15;
                    int b = xm >> 11, s = xm & 2047;
                    int h = ch & 15,  d = ch >> 4;
                    Vt[((size_t)(b * NHEADS + h) * HDIM + d) * S_LEN + s] =
                        (__bf16)acc[mi][ni][rg];
                }
    }
}

// ---------------------------------------------------------------------------
// Output projection: out[m][n] = attnb[m][:] . owt[n][:], fp32 out.
// 64x128 tiles -> grid (8,64) = 512 blocks. Swizzled LDS.
// ---------------------------------------------------------------------------
__global__ __launch_bounds__(256) void out_gemm(const __bf16* __restrict__ A,
                                                const __bf16* __restrict__ Bt,
                                                float* __restrict__ out) {
    __shared__ __bf16 As[64][32];
    __shared__ __bf16 Bs[128][32];
    int tid  = threadIdx.x;
    int wave = tid >> 6, lane = tid & 63;
    int quad = lane >> 4, l15 = lane & 15;
    int m0 = blockIdx.y * 64, n0 = blockIdx.x * 128;
    int wm = (wave >> 1) * 32, wn = (wave & 1) * 64;
    int grow = lane >> 2;
    int gcol = (((lane & 3) - ((lane >> 3) & 3)) & 3) * 8;
    int sA   = ((quad + (l15 >> 1)) & 3) * 8;
    const int K = DMODEL;
    f32x4 acc[2][4] = {};

    for (int k0 = 0; k0 < K; k0 += 32) {
        __syncthreads();
        gll16(&A[(m0 + wave * 16 + grow) * K + k0 + gcol], &As[wave * 16][0]);
#pragma unroll
        for (int ps = 0; ps < 2; ps++) {
            int row = ps * 64 + wave * 16;
            gll16(&Bt[(n0 + row + grow) * K + k0 + gcol], &Bs[row][0]);
        }
        __syncthreads();
        bf16x8 af[2], bfr[4];
#pragma unroll
        for (int mi = 0; mi < 2; mi++)
            af[mi] = *(const bf16x8*)&As[wm + mi * 16 + l15][sA];
#pragma unroll
        for (int ni = 0; ni < 4; ni++)
            bfr[ni] = *(const bf16x8*)&Bs[wn + ni * 16 + l15][sA];
#pragma unroll
        for (int mi = 0; mi < 2; mi++)
#pragma unroll
            for (int ni = 0; ni < 4; ni++)
                acc[mi][ni] = __builtin_amdgcn_mfma_f32_16x16x32_bf16(
                    af[mi], bfr[ni], acc[mi][ni], 0, 0, 0);
    }

#pragma unroll
    for (int mi = 0; mi < 2; mi++)
#pragma unroll
        for (int ni = 0; ni < 4; ni++)
#pragma unroll
            for (int rg = 0; rg < 4; rg++) {
                int m = m0 + wm + mi * 16 + quad * 4 + rg;
                int n = n0 + wn + ni * 16 + l15;
                out[(size_t)m * DMODEL + n] = acc[mi][ni][rg];
            }
}

// ---------------------------------------------------------------------------
// Flash attention (v13): 128 q-rows/block, KV range split into 2 equal
// halves -> 1024 blocks (3/CU resident, 43KB LDS). All blocks emit bf16
// partial o + f32 (m,l); combine merges. K/V frags shared across q-halves.
// id mapping: xcd=id&7, bh = xcd+8*(r&3), rr=r>>2: t=15-(rr>>1), half=rr&1.
// ---------------------------------------------------------------------------
__global__ __launch_bounds__(256, 3) void flash_attn(const __bf16* __restrict__ Qhi,
                                                     const __bf16* __restrict__ Qlo,
                                                     const __bf16* __restrict__ Khi,
                                                     const __bf16* __restrict__ Klo,
                                                     const __bf16* __restrict__ Vt,
                                                     __bf16* __restrict__ po0,
                                                     __bf16* __restrict__ po1,
                                                     float* __restrict__ pml) {
    int id  = blockIdx.x;
    int xcd = id & 7, r = id >> 3;          // r 0..127
    int bh  = xcd + 8 * (r & 3);            // 4 heads pinned per XCD
    int rr  = r >> 2;                       // 0..31
    int t   = 15 - (rr >> 1);               // longest q-tiles first
    int half = rr & 1;
    int i0 = half ? (t + 1) : 0;
    int i1 = half ? (2 * t + 2) : (t + 1);  // (t+1) iters each half
    int b = bh >> 4, h = bh & 15;
    const __bf16* Qh_hi = Qhi + (size_t)b * S_LEN * DMODEL + h * HDIM;
    const __bf16* Qh_lo = Qlo + (size_t)b * S_LEN * DMODEL + h * HDIM;
    const __bf16* Kh_hi = Khi + (size_t)b * S_LEN * DMODEL + h * HDIM;
    const __bf16* Kh_lo = Klo + (size_t)b * S_LEN * DMODEL + h * HDIM;
    const __bf16* Vh    = Vt  + (size_t)bh * HDIM * S_LEN;

    int tid = threadIdx.x, wave = tid >> 6, lane = tid & 63;
    int quad = lane >> 4, l15 = lane & 15;

    __shared__ __bf16 KhF[8 * 64 * 8];
    __shared__ __bf16 KlF[8 * 64 * 8];
    __shared__ __bf16 VF [8 * 64 * 8];
    __shared__ __bf16 Ps[4][32][72];

    int c1  = tid >> 6, key = tid & 63;
    int inner = (c1 * 16 + (key & 15)) * 8;
    int rK    = (key >> 4);
    int kdst0 = rK * 512 + inner, kdst1 = (4 + rK) * 512 + inner;
    const __bf16* vrow = Vh + (size_t)key * S_LEN;   // dim = key var

    int qbase = t * 128 + wave * 32;        // this wave's 32 q-rows
    bf16x8 aqh0[2], aqh1[2], aql0[2], aql1[2];
#pragma unroll
    for (int qh = 0; qh < 2; qh++) {
        size_t qr = (size_t)(qbase + qh * 16 + l15) * DMODEL;
        aqh0[qh] = *(const bf16x8*)&Qh_hi[qr + quad * 8];
        aqh1[qh] = *(const bf16x8*)&Qh_hi[qr + 32 + quad * 8];
        aql0[qh] = *(const bf16x8*)&Qh_lo[qr + quad * 8];
        aql1[qh] = *(const bf16x8*)&Qh_lo[qr + 32 + quad * 8];
    }

    bf16x8 ones;
#pragma unroll
    for (int j = 0; j < 8; j++) ones[j] = (__bf16)1.0f;

    uint4 pk0, pk1, pl0, pl1, pv0, pv1;
    {   // prefetch tile i0
        const __bf16* sk = Kh_hi + (size_t)(i0 * 64 + key) * DMODEL;
        const __bf16* sl = Kh_lo + (size_t)(i0 * 64 + key) * DMODEL;
        pk0 = *(const uint4*)(sk + c1 * 8); pk1 = *(const uint4*)(sk + c1 * 8 + 32);
        pl0 = *(const uint4*)(sl + c1 * 8); pl1 = *(const uint4*)(sl + c1 * 8 + 32);
        pv0 = *(const uint4*)(vrow + i0 * 64 + c1 * 8);
        pv1 = *(const uint4*)(vrow + i0 * 64 + c1 * 8 + 32);
    }

    float m[2][4] = {{-3e38f, -3e38f, -3e38f, -3e38f},
                     {-3e38f, -3e38f, -3e38f, -3e38f}};
    f32x4 o[2][4] = {};
    f32x4 ol[2] = {};

    for (int i = i0; i < i1; i++) {
        int key0 = i * 64;

        __syncthreads();
        *(uint4*)&KhF[kdst0] = pk0;  *(uint4*)&KhF[kdst1] = pk1;
        *(uint4*)&KlF[kdst0] = pl0;  *(uint4*)&KlF[kdst1] = pl1;
        *(uint4*)&VF [kdst0] = pv0;  *(uint4*)&VF [kdst1] = pv1;
        __syncthreads();

        if (i + 1 < i1) {
            int key0n = (i + 1) * 64;
            const __bf16* sk = Kh_hi + (size_t)(key0n + key) * DMODEL;
            const __bf16* sl = Kh_lo + (size_t)(key0n + key) * DMODEL;
            pk0 = *(const uint4*)(sk + c1 * 8); pk1 = *(const uint4*)(sk + c1 * 8 + 32);
            pl0 = *(const uint4*)(sl + c1 * 8); pl1 = *(const uint4*)(sl + c1 * 8 + 32);
            pv0 = *(const uint4*)(vrow + key0n + c1 * 8);
            pv1 = *(const uint4*)(vrow + key0n + c1 * 8 + 32);
        }

        // waves whose whole 32-row q-range is below this key-tile skip compute
        if (key0 > qbase + 31) continue;

        // ---- S(log2 domain) = Q K^T, split-bf16: hi.hi + hi.lo + lo.hi
        // K-frags read ONCE per ni, feed both q-halves.
        f32x4 sc[2][4] = {};
#pragma unroll
        for (int ni = 0; ni < 4; ni++) {
            bf16x8 kh0 = *(const bf16x8*)&KhF[(ni * 64 + lane) * 8];
            bf16x8 kh1 = *(const bf16x8*)&KhF[((4 + ni) * 64 + lane) * 8];
            bf16x8 kl0 = *(const bf16x8*)&KlF[(ni * 64 + lane) * 8];
            bf16x8 kl1 = *(const bf16x8*)&KlF[((4 + ni) * 64 + lane) * 8];
#pragma unroll
            for (int qh = 0; qh < 2; qh++) {
                sc[qh][ni] = __builtin_amdgcn_mfma_f32_16x16x32_bf16(aqh0[qh], kh0, sc[qh][ni], 0, 0, 0);
                sc[qh][ni] = __builtin_amdgcn_mfma_f32_16x16x32_bf16(aqh1[qh], kh1, sc[qh][ni], 0, 0, 0);
                sc[qh][ni] = __builtin_amdgcn_mfma_f32_16x16x32_bf16(aqh0[qh], kl0, sc[qh][ni], 0, 0, 0);
                sc[qh][ni] = __builtin_amdgcn_mfma_f32_16x16x32_bf16(aqh1[qh], kl1, sc[qh][ni], 0, 0, 0);
                sc[qh][ni] = __builtin_amdgcn_mfma_f32_16x16x32_bf16(aql0[qh], kh0, sc[qh][ni], 0, 0, 0);
                sc[qh][ni] = __builtin_amdgcn_mfma_f32_16x16x32_bf16(aql1[qh], kh1, sc[qh][ni], 0, 0, 0);
            }
        }

        if (i >= 2 * t) {                   // diagonal band: causal mask
#pragma unroll
            for (int qh = 0; qh < 2; qh++) {
                int qrb = qbase + qh * 16 + quad * 4;
#pragma unroll
                for (int ni = 0; ni < 4; ni++) {
                    int keyi = key0 + ni * 16 + l15;
#pragma unroll
                    for (int rg = 0; rg < 4; rg++)
                        if (keyi > qrb + rg) sc[qh][ni][rg] = -1e30f;
                }
            }
        }

        // ---- online softmax per q-half (v6-proven sequence)
#pragma unroll
        for (int qh = 0; qh < 2; qh++) {
#pragma unroll
            for (int rg = 0; rg < 4; rg++) {
                float mx = fmaxf(fmaxf(sc[qh][0][rg], sc[qh][1][rg]),
                                 fmaxf(sc[qh][2][rg], sc[qh][3][rg]));
#pragma unroll
                for (int mm = 1; mm < 16; mm <<= 1)
                    mx = fmaxf(mx, __shfl_xor(mx, mm, 64));
                float mnew  = fmaxf(m[qh][rg], mx);
                float alpha = __builtin_amdgcn_exp2f(m[qh][rg] - mnew);
                m[qh][rg] = mnew;
#pragma unroll
                for (int ni = 0; ni < 4; ni++) {
                    float px = __builtin_amdgcn_exp2f(sc[qh][ni][rg] - mnew);
                    Ps[wave][qh * 16 + quad * 4 + rg][ni * 16 + l15] = (__bf16)px;
                }
                ol[qh][rg] *= alpha;
#pragma unroll
                for (int ni = 0; ni < 4; ni++)
                    o[qh][ni][rg] *= alpha;
            }
        }

        // ---- PV: V-frags read once per (step,ni), feed both q-halves
#pragma unroll
        for (int step = 0; step < 2; step++) {
            bf16x8 ap0 = *(const bf16x8*)&Ps[wave][l15][step * 32 + quad * 8];
            bf16x8 ap1 = *(const bf16x8*)&Ps[wave][16 + l15][step * 32 + quad * 8];
            ol[0] = __builtin_amdgcn_mfma_f32_16x16x32_bf16(ap0, ones, ol[0], 0, 0, 0);
            ol[1] = __builtin_amdgcn_mfma_f32_16x16x32_bf16(ap1, ones, ol[1], 0, 0, 0);
#pragma unroll
            for (int ni = 0; ni < 4; ni++) {
                bf16x8 bv = *(const bf16x8*)&VF[((step * 4 + ni) * 64 + lane) * 8];
                o[0][ni] = __builtin_amdgcn_mfma_f32_16x16x32_bf16(ap0, bv, o[0][ni], 0, 0, 0);
                o[1][ni] = __builtin_amdgcn_mfma_f32_16x16x32_bf16(ap1, bv, o[1][ni], 0, 0, 0);
            }
        }
    }

    // ---- partial epilogue: bf16 unnormalized o + f32 per-row (m, l)
    int pslot = bh * 16 + t;                       // 0..511
    __bf16* po = half ? po1 : po0;
    float* pm = pml + ((size_t)half * 512 + pslot) * 256;
#pragma unroll
    for (int qh = 0; qh < 2; qh++)
#pragma unroll
        for (int rg = 0; rg < 4; rg++) {
            int row = wave * 32 + qh * 16 + quad * 4 + rg;   // 0..127
            if (l15 == 0) { pm[row] = m[qh][rg]; pm[128 + row] = ol[qh][rg]; }
#pragma unroll
            for (int ni = 0; ni < 4; ni++)
                po[((size_t)pslot * 128 + row) * 64 + ni * 16 + l15] =
                    (__bf16)o[qh][ni][rg];
        }
}

// ---------------------------------------------------------------------------
// Combine: merge the two KV-half partials of every q-tile.
// Grid 1024 (one block per 64-row half-tile), 256 threads: 16 dims/thread.
// ---------------------------------------------------------------------------
__global__ __launch_bounds__(256) void combine(const __bf16* __restrict__ po0,
                                               const __bf16* __restrict__ po1,
                                               const float* __restrict__ pml,
                                               __bf16* __restrict__ attn) {
    int bid = blockIdx.x;                   // 0..1023
    int pslot = bid >> 1;                   // 0..511
    int bh = pslot >> 4, t = pslot & 15;
    int b = bh >> 4, h = bh & 15;
    int tid = threadIdx.x;
    int row = (bid & 1) * 64 + (tid >> 2);  // 0..127
    int c = (tid & 3) * 16;

    const float* pm0 = pml + (size_t)pslot * 256;
    const float* pm1 = pml + (size_t)(512 + pslot) * 256;
    float m0 = pm0[row], l0 = pm0[128 + row];
    float m1 = pm1[row], l1 = pm1[128 + row];
    float mm = fmaxf(m0, m1);
    float s0 = __builtin_amdgcn_exp2f(m0 - mm);
    float s1 = __builtin_amdgcn_exp2f(m1 - mm);
    float inv = 1.0f / (l0 * s0 + l1 * s1);
    float w0 = s0 * inv, w1 = s1 * inv;

    const __bf16* r0 = po0 + ((size_t)pslot * 128 + row) * 64 + c;
    const __bf16* r1 = po1 + ((size_t)pslot * 128 + row) * 64 + c;
    int q = t * 128 + row;
    __bf16* dst = attn + ((size_t)b * S_LEN + q) * DMODEL + h * HDIM + c;
    bf16x8 a0 = *(const bf16x8*)(r0);
    bf16x8 a1 = *(const bf16x8*)(r0 + 8);
    bf16x8 b0 = *(const bf16x8*)(r1);
    bf16x8 b1 = *(const bf16x8*)(r1 + 8);
    bf16x8 d0, d1;
#pragma unroll
    for (int e = 0; e < 8; e++) {
        d0[e] = (__bf16)((float)a0[e] * w0 + (float)b0[e] * w1);
        d1[e] = (__bf16)((float)a1[e] * w0 + (float)b1[e] * w1);
    }
    *(bf16x8*)(dst)     = d0;
    *(bf16x8*)(dst + 8) = d1;
}

// ---------------------------------------------------------------------------
extern "C" void kernel_launch(void* const* d_in, const int* in_sizes, int n_in,
                              void* d_out, int out_size, void* d_ws, size_t ws_size,
                              hipStream_t stream) {
    const float* x  = (const float*)d_in[0];
    const float* qw = (const float*)d_in[1];
    const float* kw = (const float*)d_in[2];
    const float* vw = (const float*)d_in[3];
    const float* ow = (const float*)d_in[4];

    char* ws = (char*)d_ws;
    const size_t MB = 1024 * 1024;
    __bf16* xhi   = (__bf16*)(ws);             //  8 MB  [4096,1024]
    __bf16* xlo   = (__bf16*)(ws + 8 * MB);    //  8 MB  (reused as attnb later)
    __bf16* qwthi = (__bf16*)(ws + 16 * MB);   //  2 MB each
    __bf16* qwtlo = (__bf16*)(ws + 18 * MB);
    __bf16* kwthi = (__bf16*)(ws + 20 * MB);
    __bf16* kwtlo = (__bf16*)(ws + 22 * MB);
    __bf16* vwt   = (__bf16*)(ws + 24 * MB);
    __bf16* owt   = (__bf16*)(ws + 26 * MB);
    __bf16* Qhi_b = (__bf16*)(ws + 28 * MB);   //  8 MB  merged [B*S][D]
    __bf16* Qlo_b = (__bf16*)(ws + 36 * MB);
    __bf16* Khi_b = (__bf16*)(ws + 44 * MB);
    __bf16* Klo_b = (__bf16*)(ws + 52 * MB);
    __bf16* Vtb   = (__bf16*)(ws + 60 * MB);   //  8 MB  [B,H,64,S]
    __bf16* attnb = xlo;                       //  alias: xlo dead after QKV GEMMs
    // Partial buffers in regions dead once flash_attn runs:
    __bf16* po0 = (__bf16*)(ws);               //  8 MB over xhi       [512][128][64]
    __bf16* po1 = (__bf16*)(ws + 16 * MB);     //  8 MB over qwt/kwt   [512][128][64]
    float*  pml = (float*)(ws + 24 * MB);      //  1 MB over vwt       [2][512][256]

    prep_all<<<8192, 256, 0, stream>>>(x, qw, kw, vw, ow,
                                       xhi, xlo, qwthi, qwtlo, kwthi, kwtlo,
                                       vwt, owt);

    qkv_gemm<<<dim3(8, 32, 3), 256, 0, stream>>>(
        xhi, xlo, qwthi, qwtlo, kwthi, kwtlo, vwt,
        Qhi_b, Qlo_b, Khi_b, Klo_b, Vtb);

    flash_attn<<<1024, 256, 0, stream>>>(Qhi_b, Qlo_b, Khi_b, Klo_b, Vtb,
                                         po0, po1, pml);

    combine<<<1024, 256, 0, stream>>>(po0, po1, pml, attnb);

    out_gemm<<<dim3(8, 64), 256, 0, stream>>>(attnb, owt, (float*)d_out);
}

// Round 5
// 246.760 us; speedup vs baseline: 1.0908x; 1.0458x over previous
//
#include <hip/hip_runtime.h>

// ---------------------------------------------------------------------------
// MultiHeadAttention: B=2, S=2048, D=1024, H=16, hd=64
// Interleaved head split: Q[b,h,s,d] = proj[b,s, d*16+h]; scale = 1/32.
// Precision: split-bf16 (hi+lo) emulated-fp32 for Q/K path. V/attn/out bf16.
// v14: re-anchor on the proven v9 baseline (248us: v6 flash, no split-KV,
// no combine — R0-R3 restructures all regressed; 3000cyc/64x64-unit is
// invariant to LDS-demand/residency/balance => per-iter latency-bound).
// Single isolated change: s_setprio(1) around flash MFMA clusters (T5;
// regime-matched: independent blocks at different phases, m191-positive).
// ---------------------------------------------------------------------------

typedef __bf16 bf16x8 __attribute__((ext_vector_type(8)));
typedef float  f32x4  __attribute__((ext_vector_type(4)));

#define S_LEN  2048
#define DMODEL 1024
#define NHEADS 16
#define HDIM   64
#define LOG2E  1.44269504088896340736f

__device__ __forceinline__ void gll16(const __bf16* g, __bf16* l) {
    __builtin_amdgcn_global_load_lds(
        (const __attribute__((address_space(1))) unsigned int*)g,
        (__attribute__((address_space(3))) unsigned int*)l, 16, 0, 0);
}

// ---------------------------------------------------------------------------
// Fused prep: id<4096 -> f32->(hi,lo) conv of x; else weight transposes.
// z=0: qw split col-permuted; z=1: kw; z=2: vw plain; z=3: ow k-permuted.
// perm(i) = (i&15)*64 + (i>>4).
// ---------------------------------------------------------------------------
__global__ __launch_bounds__(256) void prep_all(
    const float* __restrict__ x,
    const float* __restrict__ qw, const float* __restrict__ kw,
    const float* __restrict__ vw, const float* __restrict__ ow,
    __bf16* __restrict__ xhi, __bf16* __restrict__ xlo,
    __bf16* __restrict__ qwthi, __bf16* __restrict__ qwtlo,
    __bf16* __restrict__ kwthi, __bf16* __restrict__ kwtlo,
    __bf16* __restrict__ vwt,  __bf16* __restrict__ owt) {
    __shared__ float tile[32][33];
    int id = blockIdx.x;
    if (id < 4096) {
        int i = id * 256 + threadIdx.x;
        float4 v = ((const float4*)x)[i];
        __bf16 h0 = (__bf16)v.x, h1 = (__bf16)v.y, h2 = (__bf16)v.z, h3 = (__bf16)v.w;
        ushort4 hh, ll;
        hh.x = __builtin_bit_cast(unsigned short, h0);
        hh.y = __builtin_bit_cast(unsigned short, h1);
        hh.z = __builtin_bit_cast(unsigned short, h2);
        hh.w = __builtin_bit_cast(unsigned short, h3);
        ll.x = __builtin_bit_cast(unsigned short, (__bf16)(v.x - (float)h0));
        ll.y = __builtin_bit_cast(unsigned short, (__bf16)(v.y - (float)h1));
        ll.z = __builtin_bit_cast(unsigned short, (__bf16)(v.z - (float)h2));
        ll.w = __builtin_bit_cast(unsigned short, (__bf16)(v.w - (float)h3));
        ((ushort4*)xhi)[i] = hh;
        ((ushort4*)xlo)[i] = ll;
        return;
    }
    int rid = id - 4096;
    int z = rid >> 10;                       // 0..3
    int bx = rid & 31, by = (rid >> 5) & 31;
    const float* w = (z == 0) ? qw : (z == 1) ? kw : (z == 2) ? vw : ow;
    int n0 = bx * 32, k0 = by * 32;
    int tx = threadIdx.x & 31, ty = threadIdx.x >> 5;
#pragma unroll
    for (int i = 0; i < 32; i += 8)
        tile[ty + i][tx] = w[(k0 + ty + i) * DMODEL + n0 + tx];
    __syncthreads();
#pragma unroll
    for (int i = 0; i < 32; i += 8) {
        float f = tile[tx][ty + i];           // = w[k0+tx][n0+ty+i]
        int k = k0 + tx, n = n0 + ty + i;
        if (z <= 1) {
            __bf16 fh = (__bf16)f;
            __bf16 fl = (__bf16)(f - (float)fh);
            int c = (n & 15) * 64 + (n >> 4);
            if (z == 0) { qwthi[c * DMODEL + k] = fh; qwtlo[c * DMODEL + k] = fl; }
            else        { kwthi[c * DMODEL + k] = fh; kwtlo[c * DMODEL + k] = fl; }
        } else if (z == 2) {
            vwt[n * DMODEL + k] = (__bf16)f;
        } else {
            int ck = (k & 15) * 64 + (k >> 4);
            owt[n * DMODEL + ck] = (__bf16)f;
        }
    }
}

// ---------------------------------------------------------------------------
// QKV projections. grid (8, 32, 3), LDS chunk-swizzled (2-way frag reads).
// z=0: Q = x @ qw (split-bf16, scale log2e/32), merged [m][c] hi/lo out.
// z=1: K likewise, scale 1.
// z=2: V^T = vwt @ x^T (plain), out [bh][d][s].
// ---------------------------------------------------------------------------
__global__ __launch_bounds__(256) void qkv_gemm(
    const __bf16* __restrict__ xhi, const __bf16* __restrict__ xlo,
    const __bf16* __restrict__ qwthi, const __bf16* __restrict__ qwtlo,
    const __bf16* __restrict__ kwthi, const __bf16* __restrict__ kwtlo,
    const __bf16* __restrict__ vwt,
    __bf16* __restrict__ Qhi, __bf16* __restrict__ Qlo,
    __bf16* __restrict__ Khi, __bf16* __restrict__ Klo,
    __bf16* __restrict__ Vt) {
    __shared__ __bf16 Ash[128][32], Asl[128][32], Bsh[128][32], Bsl[128][32];
    int mode = blockIdx.z;
    int tid  = threadIdx.x;
    int wave = tid >> 6, lane = tid & 63;
    int quad = lane >> 4, l15 = lane & 15;
    int wm = (wave >> 1) * 64, wn = (wave & 1) * 64;
    int grow = lane >> 2;
    int gcol = (((lane & 3) - ((lane >> 3) & 3)) & 3) * 8;   // swizzled source chunk
    int sA   = ((quad + (l15 >> 1)) & 3) * 8;                // swizzled frag slot
    const int K = DMODEL;

    if (mode < 2) {
        const __bf16* Bh = mode ? kwthi : qwthi;
        const __bf16* Bl = mode ? kwtlo : qwtlo;
        int m0 = blockIdx.y * 128, n0 = blockIdx.x * 128;
        f32x4 acc[4][4] = {};
        for (int k0 = 0; k0 < K; k0 += 32) {
            __syncthreads();
#pragma unroll
            for (int ps = 0; ps < 2; ps++) {
                int row = ps * 64 + wave * 16;
                gll16(&xhi[(m0 + row + grow) * K + k0 + gcol], &Ash[row][0]);
                gll16(&xlo[(m0 + row + grow) * K + k0 + gcol], &Asl[row][0]);
                gll16(&Bh [(n0 + row + grow) * K + k0 + gcol], &Bsh[row][0]);
                gll16(&Bl [(n0 + row + grow) * K + k0 + gcol], &Bsl[row][0]);
            }
            __syncthreads();
            bf16x8 ah[4], al[4], bh[4], bl[4];
#pragma unroll
            for (int mi = 0; mi < 4; mi++) {
                ah[mi] = *(const bf16x8*)&Ash[wm + mi * 16 + l15][sA];
                al[mi] = *(const bf16x8*)&Asl[wm + mi * 16 + l15][sA];
            }
#pragma unroll
            for (int ni = 0; ni < 4; ni++) {
                bh[ni] = *(const bf16x8*)&Bsh[wn + ni * 16 + l15][sA];
                bl[ni] = *(const bf16x8*)&Bsl[wn + ni * 16 + l15][sA];
            }
#pragma unroll
            for (int mi = 0; mi < 4; mi++)
#pragma unroll
                for (int ni = 0; ni < 4; ni++) {
                    acc[mi][ni] = __builtin_amdgcn_mfma_f32_16x16x32_bf16(ah[mi], bh[ni], acc[mi][ni], 0, 0, 0);
                    acc[mi][ni] = __builtin_amdgcn_mfma_f32_16x16x32_bf16(ah[mi], bl[ni], acc[mi][ni], 0, 0, 0);
                    acc[mi][ni] = __builtin_amdgcn_mfma_f32_16x16x32_bf16(al[mi], bh[ni], acc[mi][ni], 0, 0, 0);
                }
        }
        float oscale = mode ? 1.0f : 0.03125f * LOG2E;
        __bf16* Ohi = mode ? Khi : Qhi;
        __bf16* Olo = mode ? Klo : Qlo;
#pragma unroll
        for (int mi = 0; mi < 4; mi++)
#pragma unroll
            for (int ni = 0; ni < 4; ni++)
#pragma unroll
                for (int rg = 0; rg < 4; rg++) {
                    int m = m0 + wm + mi * 16 + quad * 4 + rg;
                    int n = n0 + wn + ni * 16 + l15;     // n == merged channel
                    float v = acc[mi][ni][rg] * oscale;
                    size_t idx = (size_t)m * DMODEL + n;
                    __bf16 vh = (__bf16)v;
                    Ohi[idx] = vh;
                    Olo[idx] = (__bf16)(v - (float)vh);
                }
    } else {
        // V^T: A = vwt (channel rows), B = xhi (x rows); C[ch][xm]
        int ch0 = blockIdx.x * 128, xm0 = blockIdx.y * 128;
        f32x4 acc[4][4] = {};
        for (int k0 = 0; k0 < K; k0 += 32) {
            __syncthreads();
#pragma unroll
            for (int ps = 0; ps < 2; ps++) {
                int row = ps * 64 + wave * 16;
                gll16(&vwt[(ch0 + row + grow) * K + k0 + gcol], &Ash[row][0]);
                gll16(&xhi[(xm0 + row + grow) * K + k0 + gcol], &Bsh[row][0]);
            }
            __syncthreads();
            bf16x8 af[4], bfr[4];
#pragma unroll
            for (int mi = 0; mi < 4; mi++)
                af[mi] = *(const bf16x8*)&Ash[wm + mi * 16 + l15][sA];
#pragma unroll
            for (int ni = 0; ni < 4; ni++)
                bfr[ni] = *(const bf16x8*)&Bsh[wn + ni * 16 + l15][sA];
#pragma unroll
            for (int mi = 0; mi < 4; mi++)
#pragma unroll
                for (int ni = 0; ni < 4; ni++)
                    acc[mi][ni] = __builtin_amdgcn_mfma_f32_16x16x32_bf16(
                        af[mi], bfr[ni], acc[mi][ni], 0, 0, 0);
        }
#pragma unroll
        for (int mi = 0; mi < 4; mi++)
#pragma unroll
            for (int ni = 0; ni < 4; ni++)
#pragma unroll
                for (int rg = 0; rg < 4; rg++) {
                    int ch = ch0 + wm + mi * 16 + quad * 4 + rg;
                    int xm = xm0 + wn + ni * 16 + l15;
                    int b = xm >> 11, s = xm & 2047;
                    int h = ch & 15,  d = ch >> 4;
                    Vt[((size_t)(b * NHEADS + h) * HDIM + d) * S_LEN + s] =
                        (__bf16)acc[mi][ni][rg];
                }
    }
}

// ---------------------------------------------------------------------------
// Output projection: out[m][n] = attnb[m][:] . owt[n][:], fp32 out.
// 64x128 tiles -> grid (8,64) = 512 blocks. Swizzled LDS.
// ---------------------------------------------------------------------------
__global__ __launch_bounds__(256) void out_gemm(const __bf16* __restrict__ A,
                                                const __bf16* __restrict__ Bt,
                                                float* __restrict__ out) {
    __shared__ __bf16 As[64][32];
    __shared__ __bf16 Bs[128][32];
    int tid  = threadIdx.x;
    int wave = tid >> 6, lane = tid & 63;
    int quad = lane >> 4, l15 = lane & 15;
    int m0 = blockIdx.y * 64, n0 = blockIdx.x * 128;
    int wm = (wave >> 1) * 32, wn = (wave & 1) * 64;
    int grow = lane >> 2;
    int gcol = (((lane & 3) - ((lane >> 3) & 3)) & 3) * 8;
    int sA   = ((quad + (l15 >> 1)) & 3) * 8;
    const int K = DMODEL;
    f32x4 acc[2][4] = {};

    for (int k0 = 0; k0 < K; k0 += 32) {
        __syncthreads();
        gll16(&A[(m0 + wave * 16 + grow) * K + k0 + gcol], &As[wave * 16][0]);
#pragma unroll
        for (int ps = 0; ps < 2; ps++) {
            int row = ps * 64 + wave * 16;
            gll16(&Bt[(n0 + row + grow) * K + k0 + gcol], &Bs[row][0]);
        }
        __syncthreads();
        bf16x8 af[2], bfr[4];
#pragma unroll
        for (int mi = 0; mi < 2; mi++)
            af[mi] = *(const bf16x8*)&As[wm + mi * 16 + l15][sA];
#pragma unroll
        for (int ni = 0; ni < 4; ni++)
            bfr[ni] = *(const bf16x8*)&Bs[wn + ni * 16 + l15][sA];
#pragma unroll
        for (int mi = 0; mi < 2; mi++)
#pragma unroll
            for (int ni = 0; ni < 4; ni++)
                acc[mi][ni] = __builtin_amdgcn_mfma_f32_16x16x32_bf16(
                    af[mi], bfr[ni], acc[mi][ni], 0, 0, 0);
    }

#pragma unroll
    for (int mi = 0; mi < 2; mi++)
#pragma unroll
        for (int ni = 0; ni < 4; ni++)
#pragma unroll
            for (int rg = 0; rg < 4; rg++) {
                int m = m0 + wm + mi * 16 + quad * 4 + rg;
                int n = n0 + wn + ni * 16 + l15;
                out[(size_t)m * DMODEL + n] = acc[mi][ni][rg];
            }
}

// ---------------------------------------------------------------------------
// Flash attention (v6 loop, proven 82.7us) — one block per 64-row q-tile.
// Grid 1024 = 4 blocks/CU; longest tiles dispatched first; 4 heads/XCD.
// v14: + s_setprio(1) around the two MFMA clusters (T5, isolated A/B).
// ---------------------------------------------------------------------------
__global__ __launch_bounds__(256, 4) void flash_attn(const __bf16* __restrict__ Qhi,
                                                     const __bf16* __restrict__ Qlo,
                                                     const __bf16* __restrict__ Khi,
                                                     const __bf16* __restrict__ Klo,
                                                     const __bf16* __restrict__ Vt,
                                                     __bf16* __restrict__ attn) {
    int id  = blockIdx.x;
    int xcd = id & 7, r = id >> 3;
    int bh  = xcd + 8 * (r & 3);           // 4 heads pinned per XCD
    int t   = 31 - (r >> 2);               // longest q-tiles dispatched first
    int b = bh >> 4, h = bh & 15;
    const __bf16* Qh_hi = Qhi + (size_t)b * S_LEN * DMODEL + h * HDIM;
    const __bf16* Qh_lo = Qlo + (size_t)b * S_LEN * DMODEL + h * HDIM;
    const __bf16* Kh_hi = Khi + (size_t)b * S_LEN * DMODEL + h * HDIM;
    const __bf16* Kh_lo = Klo + (size_t)b * S_LEN * DMODEL + h * HDIM;
    const __bf16* Vh    = Vt  + (size_t)bh * HDIM * S_LEN;

    int tid = threadIdx.x, wave = tid >> 6, lane = tid & 63;
    int quad = lane >> 4, l15 = lane & 15;
    int iters = t + 1;

    __shared__ __bf16 KhF[8 * 64 * 8];
    __shared__ __bf16 KlF[8 * 64 * 8];
    __shared__ __bf16 VF [8 * 64 * 8];
    __shared__ __bf16 Ps[4][16][72];

    int c1  = tid >> 6, key = tid & 63;
    int inner = (c1 * 16 + (key & 15)) * 8;
    int rK    = (key >> 4);
    int kdst0 = rK * 512 + inner, kdst1 = (4 + rK) * 512 + inner;
    const __bf16* vrow = Vh + (size_t)key * S_LEN;   // dim = key var

    int q0w = t * 64 + wave * 16;
    bf16x8 aqh0 = *(const bf16x8*)&Qh_hi[(size_t)(q0w + l15) * DMODEL + quad * 8];
    bf16x8 aqh1 = *(const bf16x8*)&Qh_hi[(size_t)(q0w + l15) * DMODEL + 32 + quad * 8];
    bf16x8 aql0 = *(const bf16x8*)&Qh_lo[(size_t)(q0w + l15) * DMODEL + quad * 8];
    bf16x8 aql1 = *(const bf16x8*)&Qh_lo[(size_t)(q0w + l15) * DMODEL + 32 + quad * 8];

    bf16x8 ones;
#pragma unroll
    for (int j = 0; j < 8; j++) ones[j] = (__bf16)1.0f;

    uint4 pk0, pk1, pl0, pl1, pv0, pv1;
    {   // prefetch tile kt=0
        const __bf16* sk = Kh_hi + (size_t)key * DMODEL;
        const __bf16* sl = Kh_lo + (size_t)key * DMODEL;
        pk0 = *(const uint4*)(sk + c1 * 8); pk1 = *(const uint4*)(sk + c1 * 8 + 32);
        pl0 = *(const uint4*)(sl + c1 * 8); pl1 = *(const uint4*)(sl + c1 * 8 + 32);
        pv0 = *(const uint4*)(vrow + c1 * 8); pv1 = *(const uint4*)(vrow + c1 * 8 + 32);
    }

    float m[4] = {-3e38f, -3e38f, -3e38f, -3e38f};
    f32x4 o[4] = {};
    f32x4 ol = {};
    int qrb = q0w + quad * 4;

    for (int i = 0; i < iters; i++) {
        int key0 = i * 64;
        bool diag = (i == iters - 1);

        __syncthreads();
        *(uint4*)&KhF[kdst0] = pk0;  *(uint4*)&KhF[kdst1] = pk1;
        *(uint4*)&KlF[kdst0] = pl0;  *(uint4*)&KlF[kdst1] = pl1;
        *(uint4*)&VF [kdst0] = pv0;  *(uint4*)&VF [kdst1] = pv1;
        __syncthreads();

        if (i + 1 < iters) {
            int key0n = (i + 1) * 64;
            const __bf16* sk = Kh_hi + (size_t)(key0n + key) * DMODEL;
            const __bf16* sl = Kh_lo + (size_t)(key0n + key) * DMODEL;
            pk0 = *(const uint4*)(sk + c1 * 8); pk1 = *(const uint4*)(sk + c1 * 8 + 32);
            pl0 = *(const uint4*)(sl + c1 * 8); pl1 = *(const uint4*)(sl + c1 * 8 + 32);
            pv0 = *(const uint4*)(vrow + key0n + c1 * 8);
            pv1 = *(const uint4*)(vrow + key0n + c1 * 8 + 32);
        }

        // ---- S(log2 domain) = Q K^T, split-bf16: hi.hi + hi.lo + lo.hi
        f32x4 sc[4] = {};
        __builtin_amdgcn_s_setprio(1);
#pragma unroll
        for (int ni = 0; ni < 4; ni++) {
            bf16x8 kh0 = *(const bf16x8*)&KhF[(ni * 64 + lane) * 8];
            bf16x8 kh1 = *(const bf16x8*)&KhF[((4 + ni) * 64 + lane) * 8];
            bf16x8 kl0 = *(const bf16x8*)&KlF[(ni * 64 + lane) * 8];
            bf16x8 kl1 = *(const bf16x8*)&KlF[((4 + ni) * 64 + lane) * 8];
            sc[ni] = __builtin_amdgcn_mfma_f32_16x16x32_bf16(aqh0, kh0, sc[ni], 0, 0, 0);
            sc[ni] = __builtin_amdgcn_mfma_f32_16x16x32_bf16(aqh1, kh1, sc[ni], 0, 0, 0);
            sc[ni] = __builtin_amdgcn_mfma_f32_16x16x32_bf16(aqh0, kl0, sc[ni], 0, 0, 0);
            sc[ni] = __builtin_amdgcn_mfma_f32_16x16x32_bf16(aqh1, kl1, sc[ni], 0, 0, 0);
            sc[ni] = __builtin_amdgcn_mfma_f32_16x16x32_bf16(aql0, kh0, sc[ni], 0, 0, 0);
            sc[ni] = __builtin_amdgcn_mfma_f32_16x16x32_bf16(aql1, kh1, sc[ni], 0, 0, 0);
        }
        __builtin_amdgcn_s_setprio(0);

        if (diag) {
#pragma unroll
            for (int ni = 0; ni < 4; ni++) {
                int keyi = key0 + ni * 16 + l15;
#pragma unroll
                for (int rg = 0; rg < 4; rg++)
                    if (keyi > qrb + rg) sc[ni][rg] = -1e30f;
            }
        }

#pragma unroll
        for (int rg = 0; rg < 4; rg++) {
            float mx = fmaxf(fmaxf(sc[0][rg], sc[1][rg]),
                             fmaxf(sc[2][rg], sc[3][rg]));
#pragma unroll
            for (int mm = 1; mm < 16; mm <<= 1)
                mx = fmaxf(mx, __shfl_xor(mx, mm, 64));
            float mnew  = fmaxf(m[rg], mx);
            float alpha = __builtin_amdgcn_exp2f(m[rg] - mnew);
            m[rg] = mnew;
#pragma unroll
            for (int ni = 0; ni < 4; ni++) {
                float px = __builtin_amdgcn_exp2f(sc[ni][rg] - mnew);
                Ps[wave][quad * 4 + rg][ni * 16 + l15] = (__bf16)px;
            }
            ol[rg] *= alpha;
#pragma unroll
            for (int ni = 0; ni < 4; ni++)
                o[ni][rg] *= alpha;
        }

        __builtin_amdgcn_s_setprio(1);
#pragma unroll
        for (int step = 0; step < 2; step++) {
            bf16x8 ap = *(const bf16x8*)&Ps[wave][l15][step * 32 + quad * 8];
            ol = __builtin_amdgcn_mfma_f32_16x16x32_bf16(ap, ones, ol, 0, 0, 0);
#pragma unroll
            for (int ni = 0; ni < 4; ni++) {
                bf16x8 bv = *(const bf16x8*)&VF[((step * 4 + ni) * 64 + lane) * 8];
                o[ni] = __builtin_amdgcn_mfma_f32_16x16x32_bf16(ap, bv, o[ni], 0, 0, 0);
            }
        }
        __builtin_amdgcn_s_setprio(0);
    }

    // ---- epilogue: coalesced merged-layout store
#pragma unroll
    for (int rg = 0; rg < 4; rg++) {
        float inv = 1.0f / ol[rg];
        int q = q0w + quad * 4 + rg;
#pragma unroll
        for (int ni = 0; ni < 4; ni++) {
            attn[((size_t)b * S_LEN + q) * DMODEL + h * HDIM + ni * 16 + l15] =
                (__bf16)(o[ni][rg] * inv);
        }
    }
}

// ---------------------------------------------------------------------------
extern "C" void kernel_launch(void* const* d_in, const int* in_sizes, int n_in,
                              void* d_out, int out_size, void* d_ws, size_t ws_size,
                              hipStream_t stream) {
    const float* x  = (const float*)d_in[0];
    const float* qw = (const float*)d_in[1];
    const float* kw = (const float*)d_in[2];
    const float* vw = (const float*)d_in[3];
    const float* ow = (const float*)d_in[4];

    char* ws = (char*)d_ws;
    const size_t MB = 1024 * 1024;
    __bf16* xhi   = (__bf16*)(ws);             //  8 MB  [4096,1024]
    __bf16* xlo   = (__bf16*)(ws + 8 * MB);    //  8 MB  (reused as attnb later)
    __bf16* qwthi = (__bf16*)(ws + 16 * MB);   //  2 MB each
    __bf16* qwtlo = (__bf16*)(ws + 18 * MB);
    __bf16* kwthi = (__bf16*)(ws + 20 * MB);
    __bf16* kwtlo = (__bf16*)(ws + 22 * MB);
    __bf16* vwt   = (__bf16*)(ws + 24 * MB);
    __bf16* owt   = (__bf16*)(ws + 26 * MB);
    __bf16* Qhi_b = (__bf16*)(ws + 28 * MB);   //  8 MB  merged [B*S][D]
    __bf16* Qlo_b = (__bf16*)(ws + 36 * MB);
    __bf16* Khi_b = (__bf16*)(ws + 44 * MB);
    __bf16* Klo_b = (__bf16*)(ws + 52 * MB);
    __bf16* Vtb   = (__bf16*)(ws + 60 * MB);   //  8 MB  [B,H,64,S]
    __bf16* attnb = xlo;                       //  alias: xlo dead after QKV GEMMs

    prep_all<<<8192, 256, 0, stream>>>(x, qw, kw, vw, ow,
                                       xhi, xlo, qwthi, qwtlo, kwthi, kwtlo,
                                       vwt, owt);

    qkv_gemm<<<dim3(8, 32, 3), 256, 0, stream>>>(
        xhi, xlo, qwthi, qwtlo, kwthi, kwtlo, vwt,
        Qhi_b, Qlo_b, Khi_b, Klo_b, Vtb);

    flash_attn<<<1024, 256, 0, stream>>>(Qhi_b, Qlo_b, Khi_b, Klo_b, Vtb, attnb);

    out_gemm<<<dim3(8, 64), 256, 0, stream>>>(attnb, owt, (float*)d_out);
}